// Round 1
// baseline (229.269 us; speedup 1.0000x reference)
//
#include <hip/hip_runtime.h>
#include <hip/hip_bf16.h>
#include <stdint.h>

// Problem constants: x[2,2048,1024], w_attn[3072,1024], b_attn[3072],
// w_proj[1024,1024], b_proj[1024]. out fp32 [2,2048,1024].
// H=16, hd=64, NO softmax scaling, NO mask.

typedef __attribute__((ext_vector_type(4))) float f32x4;
typedef __attribute__((ext_vector_type(8))) short bf16x8;
typedef __attribute__((ext_vector_type(8))) unsigned short u16x8;

static __device__ __forceinline__ unsigned short f2bf(float f) {
    unsigned u = __float_as_uint(f);
    u += 0x7FFFu + ((u >> 16) & 1u);          // RNE
    return (unsigned short)(u >> 16);
}
static __device__ __forceinline__ float bf2f(unsigned short h) {
    return __uint_as_float(((unsigned)h) << 16);
}

typedef const __attribute__((address_space(1))) unsigned int* gas_ptr;
typedef __attribute__((address_space(3))) unsigned int* las_ptr;
static __device__ __forceinline__ void gload_lds16(const void* g, void* l) {
    // 16B per lane, LDS dest = wave-uniform base + lane*16 (linear)
    __builtin_amdgcn_global_load_lds((gas_ptr)g, (las_ptr)l, 16, 0, 0);
}

// ---------------- converts ----------------
// split: fp32 -> (hi,lo) bf16 pair, interleaved along last axis
__global__ void split_bf16_kernel(const float* __restrict__ src,
                                  unsigned short* __restrict__ dst, int n4) {
    int i = blockIdx.x * blockDim.x + threadIdx.x;
    int stride = gridDim.x * blockDim.x;
    for (; i < n4; i += stride) {
        float4 v = ((const float4*)src)[i];
        float x[4] = {v.x, v.y, v.z, v.w};
        u16x8 o;
#pragma unroll
        for (int j = 0; j < 4; ++j) {
            unsigned short hi = f2bf(x[j]);
            float lo = x[j] - bf2f(hi);
            o[2*j]   = hi;
            o[2*j+1] = f2bf(lo);
        }
        ((u16x8*)dst)[i] = o;
    }
}

__global__ void conv_bf16_kernel(const float* __restrict__ src,
                                 unsigned short* __restrict__ dst, int n4) {
    int i = blockIdx.x * blockDim.x + threadIdx.x;
    int stride = gridDim.x * blockDim.x;
    for (; i < n4; i += stride) {
        float4 v = ((const float4*)src)[i];
        ushort4 o;
        o.x = f2bf(v.x); o.y = f2bf(v.y); o.z = f2bf(v.z); o.w = f2bf(v.w);
        ((ushort4*)dst)[i] = o;
    }
}

// ---------------- GEMM: C = A[M][K] @ B[N][K]^T + bias ----------------
// 128x128 tile, BK=64, 4 waves (2x2), 4x4 16x16x32 frags per wave.
// LDS rows 128B with XOR swizzle (row&7)<<4, staged via global_load_lds
// with pre-swizzled global source (LDS stays linear).
// MODE 0: qkv epilogue -> q2/k2 split-bf16 [bh][s][128], vT bf16 [bh][d][2048]
// MODE 1: proj epilogue -> fp32 out [M][N]
template <int MODE>
__global__ __launch_bounds__(256, 2) void gemm_bt_kernel(
    const unsigned short* __restrict__ A,
    const unsigned short* __restrict__ Bw,
    const float* __restrict__ bias,
    unsigned short* __restrict__ q2,
    unsigned short* __restrict__ k2,
    unsigned short* __restrict__ vT,
    float* __restrict__ outp,
    int N, int K)
{
    __shared__ __align__(16) unsigned char lds[32768];
    const int t  = threadIdx.x;
    const int lane = t & 63;
    const int w  = t >> 6;
    const int wr = w >> 1, wc = w & 1;
    const int lg = lane >> 4, ll = lane & 15;
    const int m0 = blockIdx.y * 128;
    const int n0 = blockIdx.x * 128;

    f32x4 acc[4][4] = {};

    const int srow  = t >> 3;   // 0..31 within a 4KB staging call (8 thr/row)
    const int sslot = t & 7;
    const unsigned short* Abase[4];
    const unsigned short* Bbase[4];
#pragma unroll
    for (int ci = 0; ci < 4; ++ci) {
        int r  = ci * 32 + srow;
        int cg = sslot ^ (r & 7);
        Abase[ci] = A  + (size_t)(m0 + r) * K + cg * 8;
        Bbase[ci] = Bw + (size_t)(n0 + r) * K + cg * 8;
    }

    for (int k0 = 0; k0 < K; k0 += 64) {
#pragma unroll
        for (int ci = 0; ci < 4; ++ci)
            gload_lds16(Abase[ci] + k0, lds + ci*4096 + (t>>6)*1024);
#pragma unroll
        for (int ci = 0; ci < 4; ++ci)
            gload_lds16(Bbase[ci] + k0, lds + 16384 + ci*4096 + (t>>6)*1024);
        __syncthreads();   // vmcnt(0) drain before barrier (compiler-inserted)

        bf16x8 af[4][2], bfr[4][2];
#pragma unroll
        for (int mt = 0; mt < 4; ++mt)
#pragma unroll
            for (int kc = 0; kc < 2; ++kc) {
                int row = wr*64 + mt*16 + ll;
                int cg  = (4*kc + lg) ^ (row & 7);
                af[mt][kc] = *(const bf16x8*)(lds + row*128 + cg*16);
            }
#pragma unroll
        for (int nt = 0; nt < 4; ++nt)
#pragma unroll
            for (int kc = 0; kc < 2; ++kc) {
                int row = wc*64 + nt*16 + ll;
                int cg  = (4*kc + lg) ^ (row & 7);
                bfr[nt][kc] = *(const bf16x8*)(lds + 16384 + row*128 + cg*16);
            }
#pragma unroll
        for (int kc = 0; kc < 2; ++kc)
#pragma unroll
            for (int mt = 0; mt < 4; ++mt)
#pragma unroll
                for (int nt = 0; nt < 4; ++nt)
                    acc[mt][nt] = __builtin_amdgcn_mfma_f32_16x16x32_bf16(
                        af[mt][kc], bfr[nt][kc], acc[mt][nt], 0, 0, 0);
        __syncthreads();
    }

#pragma unroll
    for (int mt = 0; mt < 4; ++mt)
#pragma unroll
      for (int nt = 0; nt < 4; ++nt)
#pragma unroll
        for (int r = 0; r < 4; ++r) {
            int m = m0 + wr*64 + mt*16 + 4*lg + r;
            int n = n0 + wc*64 + nt*16 + ll;
            float v = acc[mt][nt][r] + bias[n];
            if (MODE == 0) {
                int bb = m >> 11;          // batch
                int s  = m & 2047;
                int which = n >> 10;       // 0=q 1=k 2=v
                int h  = (n >> 6) & 15;
                int d  = n & 63;
                int bh = bb * 16 + h;
                if (which == 2) {
                    vT[((size_t)bh * 64 + d) * 2048 + s] = f2bf(v);
                } else {
                    unsigned short hi = f2bf(v);
                    unsigned short lo = f2bf(v - bf2f(hi));
                    unsigned short* dp = (which == 0 ? q2 : k2)
                                       + ((size_t)bh * 2048 + s) * 128 + 2*d;
                    dp[0] = hi;
                    dp[1] = lo;
                }
            } else {
                outp[(size_t)m * N + n] = v;
            }
        }
}

// ---------------- flash attention ----------------
// grid: (32 qblocks, 32 bh). 4 waves/block, each wave owns 16 q-rows.
// KBLK=64. K2 (split hi/lo, K=128) and V^T staged in swizzled LDS.
// fp32 online softmax; P->bf16 transposed through padded per-wave LDS.
__global__ __launch_bounds__(256, 2) void attn_kernel(
    const unsigned short* __restrict__ q2,
    const unsigned short* __restrict__ k2,
    const unsigned short* __restrict__ vT,
    unsigned short* __restrict__ aout)
{
    __shared__ __align__(16) unsigned char lds[16384 + 8192 + 4*2304];
    const int t = threadIdx.x, lane = t & 63, w = t >> 6;
    const int lg = lane >> 4, ll = lane & 15;
    const int bh = blockIdx.y;
    const int q0 = blockIdx.x * 64 + w * 16;

    bf16x8 qf[4];   // Q rows in registers: [16 rows][128 split-k]
    {
        const unsigned short* qp = q2 + ((size_t)bh * 2048 + q0 + ll) * 128 + lg * 8;
#pragma unroll
        for (int kc = 0; kc < 4; ++kc)
            qf[kc] = *(const bf16x8*)(qp + kc * 32);
    }

    f32x4 o[4] = {};
    float mrow[4], lrow[4];
#pragma unroll
    for (int r = 0; r < 4; ++r) { mrow[r] = -1e30f; lrow[r] = 0.f; }

    unsigned char* Klds = lds;                       // [64][256B] swz (row&15)<<4
    unsigned char* Vlds = lds + 16384;               // [64][128B] swz (row&7)<<4
    unsigned char* Plds = lds + 24576 + w * 2304;    // [16][144B] per-wave

    const int kst_row  = t >> 4;   // 0..15 (16 thr/row for 256B rows)
    const int kst_slot = t & 15;
    const int vst_row  = t >> 3;   // 0..31 (8 thr/row for 128B rows)
    const int vst_slot = t & 7;

    for (int j0 = 0; j0 < 2048; j0 += 64) {
#pragma unroll
        for (int ci = 0; ci < 4; ++ci) {
            int r  = ci * 16 + kst_row;
            int cg = kst_slot ^ (r & 15);
            gload_lds16(k2 + ((size_t)bh*2048 + j0 + r)*128 + cg*8,
                        Klds + ci*4096 + (t>>6)*1024);
        }
#pragma unroll
        for (int ci = 0; ci < 2; ++ci) {
            int r  = ci * 32 + vst_row;
            int cg = vst_slot ^ (r & 7);
            gload_lds16(vT + ((size_t)bh*64 + r)*2048 + j0 + cg*8,
                        Vlds + ci*4096 + (t>>6)*1024);
        }
        __syncthreads();

        // QK^T (split-K=128): logits near-fp32
        f32x4 sf[4] = {};
#pragma unroll
        for (int jt = 0; jt < 4; ++jt)
#pragma unroll
            for (int kc = 0; kc < 4; ++kc) {
                int row = jt*16 + ll;
                int cg  = (4*kc + lg) ^ (row & 15);
                bf16x8 kf = *(const bf16x8*)(Klds + row*256 + cg*16);
                sf[jt] = __builtin_amdgcn_mfma_f32_16x16x32_bf16(qf[kc], kf, sf[jt], 0, 0, 0);
            }

        // online softmax (rows i = 4*lg + r, reduce across ll lanes)
        float pm[4], mn[4], sc[4], rs[4];
#pragma unroll
        for (int r = 0; r < 4; ++r)
            pm[r] = fmaxf(fmaxf(sf[0][r], sf[1][r]), fmaxf(sf[2][r], sf[3][r]));
#pragma unroll
        for (int mask = 1; mask <= 8; mask <<= 1)
#pragma unroll
            for (int r = 0; r < 4; ++r)
                pm[r] = fmaxf(pm[r], __shfl_xor(pm[r], mask));
#pragma unroll
        for (int r = 0; r < 4; ++r) {
            mn[r] = fmaxf(mrow[r], pm[r]);
            sc[r] = __expf(mrow[r] - mn[r]);
            mrow[r] = mn[r];
            rs[r] = 0.f;
        }
        unsigned short pw[4][4];
#pragma unroll
        for (int jt = 0; jt < 4; ++jt)
#pragma unroll
            for (int r = 0; r < 4; ++r) {
                float p = __expf(sf[jt][r] - mn[r]);
                unsigned short pb = f2bf(p);
                pw[jt][r] = pb;
                rs[r] += bf2f(pb);   // denominator from ROUNDED weights
            }
#pragma unroll
        for (int mask = 1; mask <= 8; mask <<= 1)
#pragma unroll
            for (int r = 0; r < 4; ++r)
                rs[r] += __shfl_xor(rs[r], mask);
#pragma unroll
        for (int r = 0; r < 4; ++r) {
            lrow[r] = lrow[r] * sc[r] + rs[r];
#pragma unroll
            for (int dt = 0; dt < 4; ++dt)
                o[dt][r] *= sc[r];
        }

        // P -> LDS (transpose to A-frag layout), stride 144B kills conflicts
#pragma unroll
        for (int jt = 0; jt < 4; ++jt)
#pragma unroll
            for (int r = 0; r < 4; ++r)
                *(unsigned short*)(Plds + (4*lg + r)*144 + (ll + 16*jt)*2) = pw[jt][r];

        bf16x8 pf[2];
#pragma unroll
        for (int kc = 0; kc < 2; ++kc)
            pf[kc] = *(const bf16x8*)(Plds + ll*144 + lg*16 + kc*64);
#pragma unroll
        for (int dt = 0; dt < 4; ++dt)
#pragma unroll
            for (int kc = 0; kc < 2; ++kc) {
                int row = dt*16 + ll;
                int cg  = (4*kc + lg) ^ (row & 7);
                bf16x8 vf = *(const bf16x8*)(Vlds + row*128 + cg*16);
                o[dt] = __builtin_amdgcn_mfma_f32_16x16x32_bf16(pf[kc], vf, o[dt], 0, 0, 0);
            }
        __syncthreads();
    }

    const int bb = bh >> 4, h = bh & 15;
#pragma unroll
    for (int dt = 0; dt < 4; ++dt)
#pragma unroll
        for (int r = 0; r < 4; ++r) {
            int srow = q0 + 4*lg + r;
            int d    = ll + 16*dt;
            float val = o[dt][r] / lrow[r];
            aout[((size_t)(bb*2048 + srow)*16 + h)*64 + d] = f2bf(val);
        }
}

// ---------------- launch ----------------
extern "C" void kernel_launch(void* const* d_in, const int* in_sizes, int n_in,
                              void* d_out, int out_size, void* d_ws, size_t ws_size,
                              hipStream_t stream) {
    const float* x      = (const float*)d_in[0];
    const float* w_attn = (const float*)d_in[1];
    const float* b_attn = (const float*)d_in[2];
    const float* w_proj = (const float*)d_in[3];
    const float* b_proj = (const float*)d_in[4];
    float* out = (float*)d_out;

    // workspace layout (MB offsets): x2 0..16, w2a 16..28, wpb 28..30,
    // q2 30..46, k2 46..62, vT 62..70, a_buf 70..78  (needs 78 MB)
    unsigned char* ws = (unsigned char*)d_ws;
    unsigned short* x2  = (unsigned short*)(ws);
    unsigned short* w2a = (unsigned short*)(ws + (size_t)16*1024*1024);
    unsigned short* wpb = (unsigned short*)(ws + (size_t)28*1024*1024);
    unsigned short* q2  = (unsigned short*)(ws + (size_t)30*1024*1024);
    unsigned short* k2  = (unsigned short*)(ws + (size_t)46*1024*1024);
    unsigned short* vT  = (unsigned short*)(ws + (size_t)62*1024*1024);
    unsigned short* ab  = (unsigned short*)(ws + (size_t)70*1024*1024);

    split_bf16_kernel<<<1024, 256, 0, stream>>>(x, x2, (2*2048*1024)/4);
    split_bf16_kernel<<<1024, 256, 0, stream>>>(w_attn, w2a, (3072*1024)/4);
    conv_bf16_kernel <<<512, 256, 0, stream>>>(w_proj, wpb, (1024*1024)/4);

    gemm_bt_kernel<0><<<dim3(24, 32), 256, 0, stream>>>(
        x2, w2a, b_attn, q2, k2, vT, nullptr, 3072, 2048);

    attn_kernel<<<dim3(32, 32), 256, 0, stream>>>(q2, k2, vT, ab);

    gemm_bt_kernel<1><<<dim3(8, 32), 256, 0, stream>>>(
        ab, wpb, b_proj, nullptr, nullptr, nullptr, out, 1024, 1024);
}

// Round 2
// 170.003 us; speedup vs baseline: 1.3486x; 1.3486x over previous
//
#include <hip/hip_runtime.h>
#include <hip/hip_bf16.h>
#include <stdint.h>

// x[2,2048,1024], w_attn[3072,1024], b_attn[3072], w_proj[1024,1024],
// b_proj[1024] -> out fp32 [2,2048,1024]. H=16, hd=64, NO scale, NO mask.

typedef __attribute__((ext_vector_type(4))) float f32x4;
typedef __attribute__((ext_vector_type(8))) short bf16x8;
typedef __attribute__((ext_vector_type(8))) unsigned short u16x8;
typedef __attribute__((ext_vector_type(4))) unsigned short u16x4;

static __device__ __forceinline__ unsigned short f2bf(float f) {
    unsigned u = __float_as_uint(f);
    u += 0x7FFFu + ((u >> 16) & 1u);          // RNE
    return (unsigned short)(u >> 16);
}
static __device__ __forceinline__ float bf2f(unsigned short h) {
    return __uint_as_float(((unsigned)h) << 16);
}

typedef const __attribute__((address_space(1))) unsigned int* gas_ptr;
typedef __attribute__((address_space(3))) unsigned int* las_ptr;
static __device__ __forceinline__ void gload_lds16(const void* g, void* l) {
    __builtin_amdgcn_global_load_lds((gas_ptr)g, (las_ptr)l, 16, 0, 0);
}

// ---------------- converts ----------------
// DUP=0: (hi, lo) pairs (for x). DUP=1: (hi, hi) pairs (for w_attn) so that
// the split GEMM computes x_hi*w_hi + x_lo*w_hi = (x)*w_hi — captures the
// first-order cross term (the interleaved (lo,lo) scheme didn't).
template <int DUP>
__global__ void split_bf16_kernel(const float* __restrict__ src,
                                  unsigned short* __restrict__ dst, int n4) {
    int i = blockIdx.x * blockDim.x + threadIdx.x;
    int stride = gridDim.x * blockDim.x;
    for (; i < n4; i += stride) {
        float4 v = ((const float4*)src)[i];
        float x[4] = {v.x, v.y, v.z, v.w};
        u16x8 o;
#pragma unroll
        for (int j = 0; j < 4; ++j) {
            unsigned short hi = f2bf(x[j]);
            o[2*j] = hi;
            if (DUP) o[2*j+1] = hi;
            else     o[2*j+1] = f2bf(x[j] - bf2f(hi));
        }
        ((u16x8*)dst)[i] = o;
    }
}

__global__ void conv_bf16_kernel(const float* __restrict__ src,
                                 unsigned short* __restrict__ dst, int n4) {
    int i = blockIdx.x * blockDim.x + threadIdx.x;
    int stride = gridDim.x * blockDim.x;
    for (; i < n4; i += stride) {
        float4 v = ((const float4*)src)[i];
        ushort4 o;
        o.x = f2bf(v.x); o.y = f2bf(v.y); o.z = f2bf(v.z); o.w = f2bf(v.w);
        ((ushort4*)dst)[i] = o;
    }
}

// ---------------- GEMM: C = A[M][K] @ B[N][K]^T + bias ----------------
// 128x128 tile, BK=64, 4 waves, m97 structure (global_load_lds w=16,
// XOR-swizzled LDS via pre-swizzled global source).
// MODE 0: qkv epilogue -> q1/k1 plain bf16 [bh][s][64], vT bf16 [bh][d][2048]
// MODE 1: proj epilogue -> fp32 out [M][N]
template <int MODE>
__global__ __launch_bounds__(256, 2) void gemm_bt_kernel(
    const unsigned short* __restrict__ A,
    const unsigned short* __restrict__ Bw,
    const float* __restrict__ bias,
    unsigned short* __restrict__ q1,
    unsigned short* __restrict__ k1,
    unsigned short* __restrict__ vT,
    float* __restrict__ outp,
    int N, int K)
{
    __shared__ __align__(16) unsigned char lds[32768];
    const int t  = threadIdx.x;
    const int lane = t & 63;
    const int w  = t >> 6;
    const int wr = w >> 1, wc = w & 1;
    const int lg = lane >> 4, ll = lane & 15;
    const int m0 = blockIdx.y * 128;
    const int n0 = blockIdx.x * 128;

    f32x4 acc[4][4] = {};

    const int srow  = t >> 3;
    const int sslot = t & 7;
    const unsigned short* Abase[4];
    const unsigned short* Bbase[4];
#pragma unroll
    for (int ci = 0; ci < 4; ++ci) {
        int r  = ci * 32 + srow;
        int cg = sslot ^ (r & 7);
        Abase[ci] = A  + (size_t)(m0 + r) * K + cg * 8;
        Bbase[ci] = Bw + (size_t)(n0 + r) * K + cg * 8;
    }

    for (int k0 = 0; k0 < K; k0 += 64) {
#pragma unroll
        for (int ci = 0; ci < 4; ++ci)
            gload_lds16(Abase[ci] + k0, lds + ci*4096 + (t>>6)*1024);
#pragma unroll
        for (int ci = 0; ci < 4; ++ci)
            gload_lds16(Bbase[ci] + k0, lds + 16384 + ci*4096 + (t>>6)*1024);
        __syncthreads();

        bf16x8 af[4][2], bfr[4][2];
#pragma unroll
        for (int mt = 0; mt < 4; ++mt)
#pragma unroll
            for (int kc = 0; kc < 2; ++kc) {
                int row = wr*64 + mt*16 + ll;
                int cg  = (4*kc + lg) ^ (row & 7);
                af[mt][kc] = *(const bf16x8*)(lds + row*128 + cg*16);
            }
#pragma unroll
        for (int nt = 0; nt < 4; ++nt)
#pragma unroll
            for (int kc = 0; kc < 2; ++kc) {
                int row = wc*64 + nt*16 + ll;
                int cg  = (4*kc + lg) ^ (row & 7);
                bfr[nt][kc] = *(const bf16x8*)(lds + 16384 + row*128 + cg*16);
            }
#pragma unroll
        for (int kc = 0; kc < 2; ++kc)
#pragma unroll
            for (int mt = 0; mt < 4; ++mt)
#pragma unroll
                for (int nt = 0; nt < 4; ++nt)
                    acc[mt][nt] = __builtin_amdgcn_mfma_f32_16x16x32_bf16(
                        af[mt][kc], bfr[nt][kc], acc[mt][nt], 0, 0, 0);
        __syncthreads();
    }

#pragma unroll
    for (int mt = 0; mt < 4; ++mt)
#pragma unroll
      for (int nt = 0; nt < 4; ++nt)
#pragma unroll
        for (int r = 0; r < 4; ++r) {
            int m = m0 + wr*64 + mt*16 + 4*lg + r;
            int n = n0 + wc*64 + nt*16 + ll;
            float v = acc[mt][nt][r] + bias[n];
            if (MODE == 0) {
                int bb = m >> 11;
                int s  = m & 2047;
                int which = n >> 10;       // 0=q 1=k 2=v
                int h  = (n >> 6) & 15;
                int d  = n & 63;
                int bh = bb * 16 + h;
                if (which == 2) {
                    vT[((size_t)bh * 64 + d) * 2048 + s] = f2bf(v);
                } else {
                    unsigned short* dp = (which == 0 ? q1 : k1)
                                       + ((size_t)bh * 2048 + s) * 64 + d;
                    *dp = f2bf(v);
                }
            } else {
                outp[(size_t)m * N + n] = v;
            }
        }
}

// ---------------- flash attention (swapped QK^T, dbuf K/V) ----------------
// grid (16 qblocks, 32 bh), 512 thr = 8 waves, QBLK=128 (16 q-rows/wave),
// KVBLK=64. Swapped S^T = mfma(K, Q): lane owns q=ll -> lane-local row
// reductions (2 shfl_xor each). K/V double-buffered, prefetch before compute.
__global__ __launch_bounds__(512, 4) void attn_kernel(
    const unsigned short* __restrict__ q1,
    const unsigned short* __restrict__ k1,
    const unsigned short* __restrict__ vT,
    unsigned short* __restrict__ aout)
{
    __shared__ __align__(16) unsigned char lds[51200]; // K dbuf 16K, V dbuf 16K, P 8*2304
    const int t = threadIdx.x, lane = t & 63, w = t >> 6;
    const int lg = lane >> 4, ll = lane & 15;
    const int bh = blockIdx.y;
    const int q0 = blockIdx.x * 128 + w * 16;

    // Q in registers (B-operand layout): lane holds Q[q=ll][k=8*lg+j]
    bf16x8 qf[2];
    {
        const unsigned short* qp = q1 + ((size_t)bh*2048 + q0 + ll)*64 + lg*8;
        qf[0] = *(const bf16x8*)(qp);
        qf[1] = *(const bf16x8*)(qp + 32);
    }

    f32x4 o[4] = {};              // O[q=4lg+r][d=ll+16dt]
    float mrow = -3.0e38f, lrow = 0.f;   // softmax state for q = ll

    unsigned char* Pl = lds + 32768 + w*2304;   // per-wave [16 q][144B]

    // staging: 512 thr x 16B = 8KB/call; 8 lanes per 128B row, 64 rows
    const int sr = t >> 3, ss = t & 7;
    const int scg = ss ^ (sr & 7);
    const unsigned short* Ksrc = k1 + ((size_t)bh*2048 + sr)*64 + scg*8;
    const unsigned short* Vsrc = vT + ((size_t)bh*64 + sr)*2048 + scg*8;
    const int sdst = w*1024;

    gload_lds16(Ksrc, lds + sdst);
    gload_lds16(Vsrc, lds + 16384 + sdst);
    __syncthreads();

    const int cgk0 = (lg    ) ^ (ll & 7);  // kc=0 swizzled granule
    const int cgk1 = (lg + 4) ^ (ll & 7);  // kc=1

    for (int it = 0; it < 32; ++it) {
        const int cb = (it & 1) ? 8192 : 0;
        if (it < 31) {
            const int nb = 8192 - cb;
            gload_lds16(Ksrc + (size_t)(it+1)*4096, lds + nb + sdst);
            gload_lds16(Vsrc + (size_t)(it+1)*64,   lds + 16384 + nb + sdst);
        }

        // QK^T swapped: sf[jt] = S^T[kv = 16jt+4lg+r][q = ll]
        f32x4 sf[4] = {};
#pragma unroll
        for (int jt = 0; jt < 4; ++jt) {
            const unsigned char* kb = lds + cb + (jt*16 + ll)*128;
            bf16x8 kf0 = *(const bf16x8*)(kb + cgk0*16);
            bf16x8 kf1 = *(const bf16x8*)(kb + cgk1*16);
            sf[jt] = __builtin_amdgcn_mfma_f32_16x16x32_bf16(kf0, qf[0], sf[jt], 0, 0, 0);
            sf[jt] = __builtin_amdgcn_mfma_f32_16x16x32_bf16(kf1, qf[1], sf[jt], 0, 0, 0);
        }

        // online softmax, lane-local row (q = ll)
        float pm = fmaxf(
            fmaxf(fmaxf(fmaxf(sf[0][0],sf[0][1]), fmaxf(sf[0][2],sf[0][3])),
                  fmaxf(fmaxf(sf[1][0],sf[1][1]), fmaxf(sf[1][2],sf[1][3]))),
            fmaxf(fmaxf(fmaxf(sf[2][0],sf[2][1]), fmaxf(sf[2][2],sf[2][3])),
                  fmaxf(fmaxf(sf[3][0],sf[3][1]), fmaxf(sf[3][2],sf[3][3]))));
        pm = fmaxf(pm, __shfl_xor(pm, 16));
        pm = fmaxf(pm, __shfl_xor(pm, 32));
        const float mn = fmaxf(mrow, pm);
        const float sc = __expf(mrow - mn);
        mrow = mn;

        float rs = 0.f;
        u16x4 pk[4];
#pragma unroll
        for (int jt = 0; jt < 4; ++jt)
#pragma unroll
            for (int r = 0; r < 4; ++r) {
                float p = __expf(sf[jt][r] - mn);
                unsigned short h = f2bf(p);
                pk[jt][r] = h;
                rs += bf2f(h);     // denominator from ROUNDED weights
            }
        rs += __shfl_xor(rs, 16);
        rs += __shfl_xor(rs, 32);
        lrow = lrow * sc + rs;

        // rescale O (rows q = 4lg+r): broadcast sc from the lane owning that q
#pragma unroll
        for (int r = 0; r < 4; ++r) {
            float scb = __shfl(sc, 4*lg + r);
            o[0][r] *= scb; o[1][r] *= scb; o[2][r] *= scb; o[3][r] *= scb;
        }

        // P -> per-wave LDS: row q=ll, kv = 16jt+4lg+{0..3} packed as b64
#pragma unroll
        for (int jt = 0; jt < 4; ++jt)
            *(u16x4*)(Pl + ll*144 + jt*32 + lg*8) = pk[jt];
        bf16x8 pf0 = *(const bf16x8*)(Pl + ll*144 + lg*16);
        bf16x8 pf1 = *(const bf16x8*)(Pl + ll*144 + lg*16 + 64);

        // PV: O += P[q][kv] * V[kv][d]
#pragma unroll
        for (int dt = 0; dt < 4; ++dt) {
            const unsigned char* vb = lds + 16384 + cb + (dt*16 + ll)*128;
            bf16x8 vf0 = *(const bf16x8*)(vb + cgk0*16);
            bf16x8 vf1 = *(const bf16x8*)(vb + cgk1*16);
            o[dt] = __builtin_amdgcn_mfma_f32_16x16x32_bf16(pf0, vf0, o[dt], 0, 0, 0);
            o[dt] = __builtin_amdgcn_mfma_f32_16x16x32_bf16(pf1, vf1, o[dt], 0, 0, 0);
        }
        __syncthreads();
    }

    const int bb = bh >> 4, h = bh & 15;
    float lr[4];
#pragma unroll
    for (int r = 0; r < 4; ++r) lr[r] = __shfl(lrow, 4*lg + r);
#pragma unroll
    for (int dt = 0; dt < 4; ++dt)
#pragma unroll
        for (int r = 0; r < 4; ++r) {
            int srow = q0 + 4*lg + r;
            int d    = ll + 16*dt;
            aout[((size_t)(bb*2048 + srow)*16 + h)*64 + d] = f2bf(o[dt][r] / lr[r]);
        }
}

// ---------------- launch ----------------
extern "C" void kernel_launch(void* const* d_in, const int* in_sizes, int n_in,
                              void* d_out, int out_size, void* d_ws, size_t ws_size,
                              hipStream_t stream) {
    const float* x      = (const float*)d_in[0];
    const float* w_attn = (const float*)d_in[1];
    const float* b_attn = (const float*)d_in[2];
    const float* w_proj = (const float*)d_in[3];
    const float* b_proj = (const float*)d_in[4];
    float* out = (float*)d_out;

    // ws (MB): x2 0..16, w2a 16..28, wpb 28..30, q1 30..38, k1 38..46,
    // vT 46..54, ab 54..62
    unsigned char* ws = (unsigned char*)d_ws;
    unsigned short* x2  = (unsigned short*)(ws);
    unsigned short* w2a = (unsigned short*)(ws + (size_t)16*1024*1024);
    unsigned short* wpb = (unsigned short*)(ws + (size_t)28*1024*1024);
    unsigned short* q1  = (unsigned short*)(ws + (size_t)30*1024*1024);
    unsigned short* k1  = (unsigned short*)(ws + (size_t)38*1024*1024);
    unsigned short* vT  = (unsigned short*)(ws + (size_t)46*1024*1024);
    unsigned short* ab  = (unsigned short*)(ws + (size_t)54*1024*1024);

    split_bf16_kernel<0><<<1024, 256, 0, stream>>>(x, x2, (2*2048*1024)/4);
    split_bf16_kernel<1><<<1024, 256, 0, stream>>>(w_attn, w2a, (3072*1024)/4);
    conv_bf16_kernel  <<<512, 256, 0, stream>>>(w_proj, wpb, (1024*1024)/4);

    gemm_bt_kernel<0><<<dim3(24, 32), 256, 0, stream>>>(
        x2, w2a, b_attn, q1, k1, vT, nullptr, 3072, 2048);

    attn_kernel<<<dim3(16, 32), 512, 0, stream>>>(q1, k1, vT, ab);

    gemm_bt_kernel<1><<<dim3(8, 32), 256, 0, stream>>>(
        ab, wpb, b_proj, nullptr, nullptr, nullptr, out, 1024, 1024);
}

// Round 3
// 159.661 us; speedup vs baseline: 1.4360x; 1.0648x over previous
//
#include <hip/hip_runtime.h>
#include <hip/hip_bf16.h>
#include <stdint.h>
#include <math.h>

// x[2,2048,1024], w_attn[3072,1024], b_attn[3072], w_proj[1024,1024],
// b_proj[1024] -> out fp32 [2,2048,1024]. H=16, hd=64, NO scale, NO mask.

typedef __attribute__((ext_vector_type(4))) float f32x4;
typedef __attribute__((ext_vector_type(16))) float f32x16;
typedef __attribute__((ext_vector_type(8))) short bf16x8;
typedef __attribute__((ext_vector_type(8))) unsigned short u16x8;

static __device__ __forceinline__ unsigned short f2bf(float f) {
    unsigned u = __float_as_uint(f);
    u += 0x7FFFu + ((u >> 16) & 1u);          // RNE
    return (unsigned short)(u >> 16);
}
static __device__ __forceinline__ float bf2f(unsigned short h) {
    return __uint_as_float(((unsigned)h) << 16);
}
static __device__ __forceinline__ unsigned cvt_pk_bf16(float a, float b) {
    unsigned r;   // r = {lo16: bf16(a), hi16: bf16(b)}
    asm("v_cvt_pk_bf16_f32 %0, %1, %2" : "=v"(r) : "v"(a), "v"(b));
    return r;
}

typedef const __attribute__((address_space(1))) unsigned int* gas_ptr;
typedef __attribute__((address_space(3))) unsigned int* las_ptr;
static __device__ __forceinline__ void gload_lds16(const void* g, void* l) {
    __builtin_amdgcn_global_load_lds((gas_ptr)g, (las_ptr)l, 16, 0, 0);
}

// ---------------- converts ----------------
// DUP=0: (hi, lo) pairs (x). DUP=1: (hi, hi) pairs (w_attn): split GEMM then
// computes x_hi*w_hi + x_lo*w_hi = x*w_hi (captures first-order cross term).
template <int DUP>
__global__ void split_bf16_kernel(const float* __restrict__ src,
                                  unsigned short* __restrict__ dst, int n4) {
    int i = blockIdx.x * blockDim.x + threadIdx.x;
    int stride = gridDim.x * blockDim.x;
    for (; i < n4; i += stride) {
        float4 v = ((const float4*)src)[i];
        float x[4] = {v.x, v.y, v.z, v.w};
        u16x8 o;
#pragma unroll
        for (int j = 0; j < 4; ++j) {
            unsigned short hi = f2bf(x[j]);
            o[2*j] = hi;
            if (DUP) o[2*j+1] = hi;
            else     o[2*j+1] = f2bf(x[j] - bf2f(hi));
        }
        ((u16x8*)dst)[i] = o;
    }
}

__global__ void conv_bf16_kernel(const float* __restrict__ src,
                                 unsigned short* __restrict__ dst, int n4) {
    int i = blockIdx.x * blockDim.x + threadIdx.x;
    int stride = gridDim.x * blockDim.x;
    for (; i < n4; i += stride) {
        float4 v = ((const float4*)src)[i];
        ushort4 o;
        o.x = f2bf(v.x); o.y = f2bf(v.y); o.z = f2bf(v.z); o.w = f2bf(v.w);
        ((ushort4*)dst)[i] = o;
    }
}

// ---------------- GEMM: C = A[M][K] @ B[N][K]^T + bias ----------------
// 128x128 tile, BK=64, 4 waves, m97 structure.
// MODE 0: qkv epilogue -> q1 (scaled by log2e) / k1 bf16 [bh][s][64],
//         vT bf16 [bh][d][2048]
// MODE 1: proj epilogue -> fp32 out [M][N]
template <int MODE>
__global__ __launch_bounds__(256, 2) void gemm_bt_kernel(
    const unsigned short* __restrict__ A,
    const unsigned short* __restrict__ Bw,
    const float* __restrict__ bias,
    unsigned short* __restrict__ q1,
    unsigned short* __restrict__ k1,
    unsigned short* __restrict__ vT,
    float* __restrict__ outp,
    int N, int K)
{
    __shared__ __align__(16) unsigned char lds[32768];
    const int t  = threadIdx.x;
    const int lane = t & 63;
    const int w  = t >> 6;
    const int wr = w >> 1, wc = w & 1;
    const int lg = lane >> 4, ll = lane & 15;
    const int m0 = blockIdx.y * 128;
    const int n0 = blockIdx.x * 128;

    f32x4 acc[4][4] = {};

    const int srow  = t >> 3;
    const int sslot = t & 7;
    const unsigned short* Abase[4];
    const unsigned short* Bbase[4];
#pragma unroll
    for (int ci = 0; ci < 4; ++ci) {
        int r  = ci * 32 + srow;
        int cg = sslot ^ (r & 7);
        Abase[ci] = A  + (size_t)(m0 + r) * K + cg * 8;
        Bbase[ci] = Bw + (size_t)(n0 + r) * K + cg * 8;
    }

    for (int k0 = 0; k0 < K; k0 += 64) {
#pragma unroll
        for (int ci = 0; ci < 4; ++ci)
            gload_lds16(Abase[ci] + k0, lds + ci*4096 + (t>>6)*1024);
#pragma unroll
        for (int ci = 0; ci < 4; ++ci)
            gload_lds16(Bbase[ci] + k0, lds + 16384 + ci*4096 + (t>>6)*1024);
        __syncthreads();

        bf16x8 af[4][2], bfr[4][2];
#pragma unroll
        for (int mt = 0; mt < 4; ++mt)
#pragma unroll
            for (int kc = 0; kc < 2; ++kc) {
                int row = wr*64 + mt*16 + ll;
                int cg  = (4*kc + lg) ^ (row & 7);
                af[mt][kc] = *(const bf16x8*)(lds + row*128 + cg*16);
            }
#pragma unroll
        for (int nt = 0; nt < 4; ++nt)
#pragma unroll
            for (int kc = 0; kc < 2; ++kc) {
                int row = wc*64 + nt*16 + ll;
                int cg  = (4*kc + lg) ^ (row & 7);
                bfr[nt][kc] = *(const bf16x8*)(lds + 16384 + row*128 + cg*16);
            }
#pragma unroll
        for (int kc = 0; kc < 2; ++kc)
#pragma unroll
            for (int mt = 0; mt < 4; ++mt)
#pragma unroll
                for (int nt = 0; nt < 4; ++nt)
                    acc[mt][nt] = __builtin_amdgcn_mfma_f32_16x16x32_bf16(
                        af[mt][kc], bfr[nt][kc], acc[mt][nt], 0, 0, 0);
        __syncthreads();
    }

#pragma unroll
    for (int mt = 0; mt < 4; ++mt)
#pragma unroll
      for (int nt = 0; nt < 4; ++nt)
#pragma unroll
        for (int r = 0; r < 4; ++r) {
            int m = m0 + wr*64 + mt*16 + 4*lg + r;
            int n = n0 + wc*64 + nt*16 + ll;
            float v = acc[mt][nt][r] + bias[n];
            if (MODE == 0) {
                int bb = m >> 11;
                int s  = m & 2047;
                int which = n >> 10;       // 0=q 1=k 2=v
                int h  = (n >> 6) & 15;
                int d  = n & 63;
                int bh = bb * 16 + h;
                if (which == 2) {
                    vT[((size_t)bh * 64 + d) * 2048 + s] = f2bf(v);
                } else {
                    // q pre-scaled by log2(e): attn uses exp2 directly
                    float vq = (which == 0) ? v * 1.44269504f : v;
                    unsigned short* dp = (which == 0 ? q1 : k1)
                                       + ((size_t)bh * 2048 + s) * 64 + d;
                    *dp = f2bf(vq);
                }
            } else {
                outp[(size_t)m * N + n] = v;
            }
        }
}

// ---------------- flash attention v3 ----------------
// 32x32x16 MFMA, max-free softmax (accumulate raw exp2, divide at end).
// grid (16 qblocks, 32 bh), 4 waves/block, each wave owns 32 q-rows.
// KVBLK=64, K/V double-buffered in swizzled LDS (gload_lds staging).
// Swapped QK^T: sacc = mfma(K, Q) = S^T[kv][q]; lane owns q-col = lane&31.
__global__ __launch_bounds__(256, 2) void attn_kernel(
    const unsigned short* __restrict__ q1,   // [bh][2048][64], pre-scaled log2e
    const unsigned short* __restrict__ k1,   // [bh][2048][64]
    const unsigned short* __restrict__ vT,   // [bh][64][2048]
    unsigned short* __restrict__ aout)       // [b][s][h][64] bf16
{
    __shared__ __align__(16) unsigned char lds[51200];
    const int t = threadIdx.x, lane = t & 63, w = t >> 6;
    const int hi = lane >> 5, lq = lane & 31, l7 = lane & 7;
    const int bh = blockIdx.y;
    const int q0 = blockIdx.x * 128 + w * 32;

    // Q B-frag: qf[ks] = Q[q0+lq][16ks + 8hi + j], j=0..7
    bf16x8 qf[4];
    {
        const unsigned short* qp = q1 + ((size_t)bh*2048 + q0 + lq)*64 + hi*8;
#pragma unroll
        for (int ks = 0; ks < 4; ++ks)
            qf[ks] = *(const bf16x8*)(qp + ks*16);
    }

    f32x16 o[2] = {};      // O[dh]: row q=(r&3)+8(r>>2)+4hi, col d=dh*32+lq
    float lrow = 0.f;      // softmax denominator for q = lq

    unsigned char* Pl = lds + 32768 + w*4608;   // per-wave P [32 q][144B]

    // staging: 256 thr x 16B = 4KB/call; rows 0..31 per call (8 thr/row)
    const int sr = t >> 3, ss = t & 7;
    const int scg = ss ^ (sr & 7);
    const unsigned short* Ksrc = k1 + ((size_t)bh*2048 + sr)*64 + scg*8;
    const unsigned short* Vsrc = vT + ((size_t)bh*64 + sr)*2048 + scg*8;
    const int sdst = w*1024;

    gload_lds16(Ksrc,         lds + sdst);
    gload_lds16(Ksrc + 2048,  lds + 4096 + sdst);          // rows 32..63
    gload_lds16(Vsrc,         lds + 16384 + sdst);
    gload_lds16(Vsrc + 65536, lds + 16384 + 4096 + sdst);  // d rows 32..63
    __syncthreads();

    for (int it = 0; it < 32; ++it) {
        const int cb = (it & 1) ? 8192 : 0;
        if (it < 31) {
            const int nb = 8192 - cb;
            const size_t ko = (size_t)(it + 1) * 4096;
            gload_lds16(Ksrc + ko,        lds + nb + sdst);
            gload_lds16(Ksrc + ko + 2048, lds + nb + 4096 + sdst);
            gload_lds16(Vsrc + (it+1)*64,         lds + 16384 + nb + sdst);
            gload_lds16(Vsrc + (it+1)*64 + 65536, lds + 16384 + nb + 4096 + sdst);
        }

        // QK^T: sacc[jt] = S^T[kv = 32jt + crow][q = lq] (exp2 domain)
        f32x16 sacc[2] = {};
#pragma unroll
        for (int jt = 0; jt < 2; ++jt) {
            const unsigned char* kb = lds + cb + (jt*32 + lq)*128;
#pragma unroll
            for (int ks = 0; ks < 4; ++ks) {
                int g = (2*ks + hi) ^ l7;
                bf16x8 kf = *(const bf16x8*)(kb + g*16);
                sacc[jt] = __builtin_amdgcn_mfma_f32_32x32x16_bf16(
                    kf, qf[ks], sacc[jt], 0, 0, 0);
            }
        }

        // max-free softmax: p = exp2(s'), accumulate denominator
        float ps[2][16];
        float rs = 0.f;
#pragma unroll
        for (int jt = 0; jt < 2; ++jt)
#pragma unroll
            for (int r = 0; r < 16; ++r) {
                float p = exp2f(sacc[jt][r]);
                ps[jt][r] = p;
                rs += p;
            }
        rs += __shfl_xor(rs, 32);   // halves own complementary kv sets
        lrow += rs;

        // P -> per-wave LDS: reg r=4g+i is kv = 32jt + 8g + 4hi + i (i=0..3)
#pragma unroll
        for (int jt = 0; jt < 2; ++jt)
#pragma unroll
            for (int g = 0; g < 4; ++g) {
                unsigned w0 = cvt_pk_bf16(ps[jt][4*g],   ps[jt][4*g+1]);
                unsigned w1 = cvt_pk_bf16(ps[jt][4*g+2], ps[jt][4*g+3]);
                *(uint2*)(Pl + lq*144 + (32*jt + 8*g + 4*hi)*2) =
                    make_uint2(w0, w1);
            }

        // P A-frags: pa[ks] = P[q=lq][kv = 16ks + 8hi + j]
        bf16x8 pa[4];
#pragma unroll
        for (int ks = 0; ks < 4; ++ks)
            pa[ks] = *(const bf16x8*)(Pl + lq*144 + ks*32 + hi*16);

        // PV: O[dh] += P * V   (V B-frag from V^T rows = d)
#pragma unroll
        for (int dh = 0; dh < 2; ++dh) {
            const unsigned char* vb = lds + 16384 + cb + (dh*32 + lq)*128;
#pragma unroll
            for (int ks = 0; ks < 4; ++ks) {
                int g = (2*ks + hi) ^ l7;
                bf16x8 vf = *(const bf16x8*)(vb + g*16);
                o[dh] = __builtin_amdgcn_mfma_f32_32x32x16_bf16(
                    pa[ks], vf, o[dh], 0, 0, 0);
            }
        }
        __syncthreads();
    }

    const int bb = bh >> 4, h = bh & 15;
#pragma unroll
    for (int r = 0; r < 16; ++r) {
        int qrow = (r & 3) + 8*(r >> 2) + 4*hi;
        float linv = 1.0f / __shfl(lrow, qrow);
        size_t srow = q0 + qrow;
#pragma unroll
        for (int dh = 0; dh < 2; ++dh) {
            int d = dh*32 + lq;
            aout[((size_t)(bb*2048 + srow)*16 + h)*64 + d] = f2bf(o[dh][r] * linv);
        }
    }
}

// ---------------- launch ----------------
extern "C" void kernel_launch(void* const* d_in, const int* in_sizes, int n_in,
                              void* d_out, int out_size, void* d_ws, size_t ws_size,
                              hipStream_t stream) {
    const float* x      = (const float*)d_in[0];
    const float* w_attn = (const float*)d_in[1];
    const float* b_attn = (const float*)d_in[2];
    const float* w_proj = (const float*)d_in[3];
    const float* b_proj = (const float*)d_in[4];
    float* out = (float*)d_out;

    // ws (MB): x2 0..16, w2a 16..28, wpb 28..30, q1 30..38, k1 38..46,
    // vT 46..54, ab 54..62
    unsigned char* ws = (unsigned char*)d_ws;
    unsigned short* x2  = (unsigned short*)(ws);
    unsigned short* w2a = (unsigned short*)(ws + (size_t)16*1024*1024);
    unsigned short* wpb = (unsigned short*)(ws + (size_t)28*1024*1024);
    unsigned short* q1  = (unsigned short*)(ws + (size_t)30*1024*1024);
    unsigned short* k1  = (unsigned short*)(ws + (size_t)38*1024*1024);
    unsigned short* vT  = (unsigned short*)(ws + (size_t)46*1024*1024);
    unsigned short* ab  = (unsigned short*)(ws + (size_t)54*1024*1024);

    split_bf16_kernel<0><<<1024, 256, 0, stream>>>(x, x2, (2*2048*1024)/4);
    split_bf16_kernel<1><<<1024, 256, 0, stream>>>(w_attn, w2a, (3072*1024)/4);
    conv_bf16_kernel  <<<512, 256, 0, stream>>>(w_proj, wpb, (1024*1024)/4);

    gemm_bt_kernel<0><<<dim3(24, 32), 256, 0, stream>>>(
        x2, w2a, b_attn, q1, k1, vT, nullptr, 3072, 2048);

    attn_kernel<<<dim3(16, 32), 256, 0, stream>>>(q1, k1, vT, ab);

    gemm_bt_kernel<1><<<dim3(8, 32), 256, 0, stream>>>(
        ab, wpb, b_proj, nullptr, nullptr, nullptr, out, 1024, 1024);
}

// Round 4
// 127.846 us; speedup vs baseline: 1.7933x; 1.2488x over previous
//
#include <hip/hip_runtime.h>
#include <hip/hip_bf16.h>
#include <stdint.h>
#include <math.h>

// x[2,2048,1024], w_attn[3072,1024], b_attn[3072], w_proj[1024,1024],
// b_proj[1024] -> out fp32 [2,2048,1024]. H=16, hd=64, NO scale, NO mask.

typedef __attribute__((ext_vector_type(4))) float f32x4;
typedef __attribute__((ext_vector_type(16))) float f32x16;
typedef __attribute__((ext_vector_type(8))) short bf16x8;

static __device__ __forceinline__ unsigned short f2bf(float f) {
    unsigned u = __float_as_uint(f);
    u += 0x7FFFu + ((u >> 16) & 1u);          // RNE
    return (unsigned short)(u >> 16);
}
static __device__ __forceinline__ unsigned cvt_pk_bf16(float a, float b) {
    unsigned r;   // r = {lo16: bf16(a), hi16: bf16(b)}
    asm("v_cvt_pk_bf16_f32 %0, %1, %2" : "=v"(r) : "v"(a), "v"(b));
    return r;
}

typedef const __attribute__((address_space(1))) unsigned int* gas_ptr;
typedef __attribute__((address_space(3))) unsigned int* las_ptr;
static __device__ __forceinline__ void gload_lds16(const void* g, void* l) {
    __builtin_amdgcn_global_lo\
ad_lds((gas_ptr)g, (las_ptr)l, 16, 0, 0);
}

// ---------------- convert fp32 -> bf16 ----------------
__global__ void conv_bf16_kernel(const float* __restrict__ src,
                                 unsigned short* __restrict__ dst, int n4) {
    int i = blockIdx.x * blockDim.x + threadIdx.x;
    int stride = gridDim.x * blockDim.x;
    for (; i < n4; i += stride) {
        float4 v = ((const float4*)src)[i];
        ushort4 o;
        o.x = f2bf(v.x); o.y = f2bf(v.y); o.z = f2bf(v.z); o.w = f2bf(v.w);
        ((ushort4*)dst)[i] = o;
    }
}

// ---------------- GEMM: C = A[M][K] @ B[N][K]^T + bias ----------------
// 128x128 tile, BK=64, 4 waves, m97 structure (global_load_lds w=16,
// XOR-swizzled LDS via pre-swizzled global source).
// MODE 0: qkv epilogue -> q1 (scaled log2e) / k1 bf16 [bh][s][64],
//         vT bf16 [bh][d][2048]
// MODE 1: proj epilogue -> fp32 out [M][N]
template <int MODE>
__global__ __launch_bounds__(256, 2) void gemm_bt_kernel(
    const unsigned short* __restrict__ A,
    const unsigned short* __restrict__ Bw,
    const float* __restrict__ bias,
    unsigned short* __restrict__ q1,
    unsigned short* __restrict__ k1,
    unsigned short* __restrict__ vT,
    float* __restrict__ outp,
    int N, int K)
{
    __shared__ __align__(16) unsigned char lds[32768];
    const int t  = threadIdx.x;
    const int lane = t & 63;
    const int w  = t >> 6;
    const int wr = w >> 1, wc = w & 1;
    const int lg = lane >> 4, ll = lane & 15;
    const int m0 = blockIdx.y * 128;
    const int n0 = blockIdx.x * 128;

    f32x4 acc[4][4] = {};

    const int srow  = t >> 3;
    const int sslot = t & 7;
    const unsigned short* Abase[4];
    const unsigned short* Bbase[4];
#pragma unroll
    for (int ci = 0; ci < 4; ++ci) {
        int r  = ci * 32 + srow;
        int cg = sslot ^ (r & 7);
        Abase[ci] = A  + (size_t)(m0 + r) * K + cg * 8;
        Bbase[ci] = Bw + (size_t)(n0 + r) * K + cg * 8;
    }

    for (int k0 = 0; k0 < K; k0 += 64) {
#pragma unroll
        for (int ci = 0; ci < 4; ++ci)
            gload_lds16(Abase[ci] + k0, lds + ci*4096 + (t>>6)*1024);
#pragma unroll
        for (int ci = 0; ci < 4; ++ci)
            gload_lds16(Bbase[ci] + k0, lds + 16384 + ci*4096 + (t>>6)*1024);
        __syncthreads();

        bf16x8 af[4][2], bfr[4][2];
#pragma unroll
        for (int mt = 0; mt < 4; ++mt)
#pragma unroll
            for (int kc = 0; kc < 2; ++kc) {
                int row = wr*64 + mt*16 + ll;
                int cg  = (4*kc + lg) ^ (row & 7);
                af[mt][kc] = *(const bf16x8*)(lds + row*128 + cg*16);
            }
#pragma unroll
        for (int nt = 0; nt < 4; ++nt)
#pragma unroll
            for (int kc = 0; kc < 2; ++kc) {
                int row = wc*64 + nt*16 + ll;
                int cg  = (4*kc + lg) ^ (row & 7);
                bfr[nt][kc] = *(const bf16x8*)(lds + 16384 + row*128 + cg*16);
            }
#pragma unroll
        for (int kc = 0; kc < 2; ++kc)
#pragma unroll
            for (int mt = 0; mt < 4; ++mt)
#pragma unroll
                for (int nt = 0; nt < 4; ++nt)
                    acc[mt][nt] = __builtin_amdgcn_mfma_f32_16x16x32_bf16(
                        af[mt][kc], bfr[nt][kc], acc[mt][nt], 0, 0, 0);
        __syncthreads();
    }

#pragma unroll
    for (int mt = 0; mt < 4; ++mt)
#pragma unroll
      for (int nt = 0; nt < 4; ++nt)
#pragma unroll
        for (int r = 0; r < 4; ++r) {
            int m = m0 + wr*64 + mt*16 + 4*lg + r;
            int n = n0 + wc*64 + nt*16 + ll;
            float v = acc[mt][nt][r] + bias[n];
            if (MODE == 0) {
                int bb = m >> 11;
                int s  = m & 2047;
                int which = n >> 10;       // 0=q 1=k 2=v
                int h  = (n >> 6) & 15;
                int d  = n & 63;
                int bh = bb * 16 + h;
                if (which == 2) {
                    vT[((size_t)bh * 64 + d) * 2048 + s] = f2bf(v);
                } else {
                    // q pre-scaled by log2(e): attn uses exp2 directly
                    float vq = (which == 0) ? v * 1.44269504f : v;
                    unsigned short* dp = (which == 0 ? q1 : k1)
                                       + ((size_t)bh * 2048 + s) * 64 + d;
                    *dp = f2bf(vq);
                }
            } else {
                outp[(size_t)m * N + n] = v;
            }
        }
}

// ---------------- flash attention v4 ----------------
// 32x32x16 MFMA, max-free softmax (exp2 accumulation, divide at end).
// grid (16 qblocks, 32 bh), 512 thr = 8 waves. kv-split: waves 0-3 (gp=0)
// process even kv-tiles, waves 4-7 odd tiles, same 128 q-rows; partials
// merged through LDS at the end (pure add thanks to max-free softmax).
// K staged with row permute pi = swap(bit2,bit3): the swapped-QK^T output
// then lands each lane's P values directly in its PV A-frag slots ->
// no P LDS, no cross-lane exchange.
__global__ __launch_bounds__(512, 4) void attn_kernel(
    const unsigned short* __restrict__ q1,   // [bh][2048][64], pre-scaled
    const unsigned short* __restrict__ k1,   // [bh][2048][64]
    const unsigned short* __restrict__ vT,   // [bh][64][2048]
    unsigned short* __restrict__ aout)       // [b][s][h][64] bf16
{
    __shared__ __align__(16) unsigned char lds[65536];
    const int t = threadIdx.x, lane = t & 63, w = t >> 6;
    const int hi = lane >> 5, lq = lane & 31, l7 = lane & 7;
    const int gp = w >> 2, sw = w & 3;
    const int bh = blockIdx.y;
    const int q0 = blockIdx.x * 128 + sw * 32;

    // Q B-frag: qf[ks][j] = Q[q0+lq][16ks + 8hi + j]
    bf16x8 qf[4];
    {
        const unsigned short* qp = q1 + ((size_t)bh*2048 + q0 + lq)*64 + hi*8;
#pragma unroll
        for (int ks = 0; ks < 4; ++ks)
            qf[ks] = *(const bf16x8*)(qp + ks*16);
    }

    f32x16 o[2] = {};      // O: row q=(r&3)+8(r>>2)+4hi, col d=dh*32+lq
    float lrow = 0.f;      // denominator for q = lq (own kv half)

    // staging: 512 thr x 16B = 8KB = one tile per gload round.
    // K rows permuted by pi(sr) = swap bits 2,3 (LDS stays linear).
    const int sr = t >> 3, ss = t & 7;
    const int scg = ss ^ (sr & 7);
    const int psr = (sr & 51) | ((sr & 4) << 1) | ((sr & 8) >> 1);
    const unsigned short* Ksrc = k1 + ((size_t)bh*2048 + psr)*64 + scg*8;
    const unsigned short* Vsrc = vT + ((size_t)bh*64 + sr)*2048 + scg*8;
    const int sdst = w*1024;

    // buffers: K at lds + b*8192 (b = (s&1)*2 + parity), V at +32768
    gload_lds16(Ksrc,        lds + sdst);
    gload_lds16(Ksrc + 4096, lds + 8192 + sdst);
    gload_lds16(Vsrc,        lds + 32768 + sdst);
    gload_lds16(Vsrc + 64,   lds + 32768 + 8192 + sdst);
    __syncthreads();

    for (int s = 0; s < 16; ++s) {
        const int cbuf = ((s & 1)*2 + gp) * 8192;
        if (s < 15) {
            const int nb = (((s+1) & 1)*2) * 8192;
            const size_t T2 = 2*s + 2;
            gload_lds16(Ksrc + T2*4096,       lds + nb + sdst);
            gload_lds16(Ksrc + (T2+1)*4096,   lds + nb + 8192 + sdst);
            gload_lds16(Vsrc + T2*64,         lds + 32768 + nb + sdst);
            gload_lds16(Vsrc + (T2+1)*64,     lds + 32768 + nb + 8192 + sdst);
        }
        const unsigned char* Kb = lds + cbuf;
        const unsigned char* Vb = lds + 32768 + cbuf;

        // QK^T swapped: sacc[jt] reg r = S^T[lds-row 32jt+crow][q=lq]
        f32x16 sacc[2] = {};
#pragma unroll
        for (int jt = 0; jt < 2; ++jt) {
            const unsigned char* kb = Kb + (jt*32 + lq)*128;
#pragma unroll
            for (int ks = 0; ks < 4; ++ks) {
                int g = (2*ks + hi) ^ l7;
                bf16x8 kf = *(const bf16x8*)(kb + g*16);
                sacc[jt] = __builtin_amdgcn_mfma_f32_32x32x16_bf16(
                    kf, qf[ks], sacc[jt], 0, 0, 0);
            }
        }

        // max-free softmax + in-register P pack (exchange-free via pi):
        // pa[2jt+u][j] = bf16(exp2(sacc[jt][8u + j]))
        float a0 = 0.f, a1 = 0.f, a2 = 0.f, a3 = 0.f;
        bf16x8 pa[4];
#pragma unroll
        for (int jt = 0; jt < 2; ++jt) {
            float ps[16];
#pragma unroll
            for (int c = 0; c < 4; ++c) {
                ps[4*c]   = exp2f(sacc[jt][4*c]);
                ps[4*c+1] = exp2f(sacc[jt][4*c+1]);
                ps[4*c+2] = exp2f(sacc[jt][4*c+2]);
                ps[4*c+3] = exp2f(sacc[jt][4*c+3]);
                a0 += ps[4*c]; a1 += ps[4*c+1]; a2 += ps[4*c+2]; a3 += ps[4*c+3];
            }
            union { unsigned u[4]; bf16x8 v; } pk0, pk1;
#pragma unroll
            for (int c = 0; c < 4; ++c) {
                pk0.u[c] = cvt_pk_bf16(ps[2*c],     ps[2*c + 1]);
                pk1.u[c] = cvt_pk_bf16(ps[8 + 2*c], ps[8 + 2*c + 1]);
            }
            pa[2*jt]     = pk0.v;
            pa[2*jt + 1] = pk1.v;
        }
        float rs = (a0 + a1) + (a2 + a3);
        rs += __shfl_xor(rs, 32);
        lrow += rs;

        // PV: O += P * V
#pragma unroll
        for (int dh = 0; dh < 2; ++dh) {
            const unsigned char* vb = Vb + (dh*32 + lq)*128;
#pragma unroll
            for (int ks = 0; ks < 4; ++ks) {
                int g = (2*ks + hi) ^ l7;
                bf16x8 vf = *(const bf16x8*)(vb + g*16);
                o[dh] = __builtin_amdgcn_mfma_f32_32x32x16_bf16(
                    pa[ks], vf, o[dh], 0, 0, 0);
            }
        }
        __syncthreads();
    }

    // ---- combine kv-split partials (pure add: max-free softmax) ----
    if (gp == 1) {
        unsigned char* p = lds + sw*9216 + lane*144;
#pragma unroll
        for (int dh = 0; dh < 2; ++dh)
#pragma unroll
            for (int c = 0; c < 4; ++c) {
                f32x4 v;
                v[0] = o[dh][4*c]; v[1] = o[dh][4*c+1];
                v[2] = o[dh][4*c+2]; v[3] = o[dh][4*c+3];
                *(f32x4*)(p + dh*64 + c*16) = v;
            }
        *(float*)(lds + 36864 + sw*256 + lane*4) = lrow;
    }
    __syncthreads();
    if (gp == 0) {
        const unsigned char* p = lds + sw*9216 + lane*144;
#pragma unroll
        for (int dh = 0; dh < 2; ++dh)
#pragma unroll
            for (int c = 0; c < 4; ++c) {
                f32x4 v = *(const f32x4*)(p + dh*64 + c*16);
                o[dh][4*c]   += v[0]; o[dh][4*c+1] += v[1];
                o[dh][4*c+2] += v[2]; o[dh][4*c+3] += v[3];
            }
        lrow += *(const float*)(lds + 36864 + sw*256 + lane*4);

        const int bb = bh >> 4, h = bh & 15;
#pragma unroll
        for (int r = 0; r < 16; ++r) {
            int qrow = (r & 3) + 8*(r >> 2) + 4*hi;
            float linv = 1.0f / __shfl(lrow, qrow);
            size_t srow = q0 + qrow;
#pragma unroll
            for (int dh = 0; dh < 2; ++dh) {
                int d = dh*32 + lq;
                aout[((size_t)(bb*2048 + srow)*16 + h)*64 + d] =
                    f2bf(o[dh][r] * linv);
            }
        }
    }
}

// ---------------- launch ----------------
extern "C" void kernel_launch(void* const* d_in, const int* in_sizes, int n_in,
                              void* d_out, int out_size, void* d_ws, size_t ws_size,
                              hipStream_t stream) {
    const float* x      = (const float*)d_in[0];
    const float* w_attn = (const float*)d_in[1];
    const float* b_attn = (const float*)d_in[2];
    const float* w_proj = (const float*)d_in[3];
    const float* b_proj = (const float*)d_in[4];
    float* out = (float*)d_out;

    // ws (MB): x1 0..8, w1a 8..14, wpb 14..16, q1 16..24, k1 24..32,
    // vT 32..40, ab 40..48
    unsigned char* ws = (unsigned char*)d_ws;
    unsigned short* x1  = (unsigned short*)(ws);
    unsigned short* w1a = (unsigned short*)(ws + (size_t)8*1024*1024);
    unsigned short* wpb = (unsigned short*)(ws + (size_t)14*1024*1024);
    unsigned short* q1  = (unsigned short*)(ws + (size_t)16*1024*1024);
    unsigned short* k1  = (unsigned short*)(ws + (size_t)24*1024*1024);
    unsigned short* vT  = (unsigned short*)(ws + (size_t)32*1024*1024);
    unsigned short* ab  = (unsigned short*)(ws + (size_t)40*1024*1024);

    conv_bf16_kernel<<<1024, 256, 0, stream>>>(x, x1, 1048576);
    conv_bf16_kernel<<<768, 256, 0, stream>>>(w_attn, w1a, 786432);
    conv_bf16_kernel<<<256, 256, 0, stream>>>(w_proj, wpb, 262144);

    gemm_bt_kernel<0><<<dim3(24, 32), 256, 0, stream>>>(
        x1, w1a, b_attn, q1, k1, vT, nullptr, 3072, 1024);

    attn_kernel<<<dim3(16, 32), 512, 0, stream>>>(q1, k1, vT, ab);

    gemm_bt_kernel<1><<<dim3(8, 32), 256, 0, stream>>>(
        ab, wpb, b_proj, nullptr, nullptr, nullptr, out, 1024, 1024);
}

// Round 5
// 125.255 us; speedup vs baseline: 1.8304x; 1.0207x over previous
//
#include <hip/hip_runtime.h>
#include <hip/hip_bf16.h>
#include <stdint.h>
#include <math.h>

// x[2,2048,1024], w_attn[3072,1024], b_attn[3072], w_proj[1024,1024],
// b_proj[1024] -> out fp32 [2,2048,1024]. H=16, hd=64, NO scale, NO mask.

typedef __attribute__((ext_vector_type(4))) float f32x4;
typedef __attribute__((ext_vector_type(16))) float f32x16;
typedef __attribute__((ext_vector_type(8))) short bf16x8;

static __device__ __forceinline__ unsigned short f2bf(float f) {
    unsigned u = __float_as_uint(f);
    u += 0x7FFFu + ((u >> 16) & 1u);          // RNE
    return (unsigned short)(u >> 16);
}
static __device__ __forceinline__ unsigned cvt_pk_bf16(float a, float b) {
    unsigned r;   // r = {lo16: bf16(a), hi16: bf16(b)}
    asm("v_cvt_pk_bf16_f32 %0, %1, %2" : "=v"(r) : "v"(a), "v"(b));
    return r;
}

typedef const __attribute__((address_space(1))) unsigned int* gas_ptr;
typedef __attribute__((address_space(3))) unsigned int* las_ptr;
static __device__ __forceinline__ void gload_lds16(const void* g, void* l) {
    __builtin_amdgcn_global_load_lds((gas_ptr)g, (las_ptr)l, 16, 0, 0);
}

// ---------------- fused fp32 -> bf16 convert (x, w_attn, w_proj) ----------------
__global__ void conv_all_kernel(const float* __restrict__ x,
                                const float* __restrict__ wa,
                                const float* __restrict__ wp,
                                unsigned short* __restrict__ x1,
                                unsigned short* __restrict__ w1a,
                                unsigned short* __restrict__ wpb) {
    int i = blockIdx.x * blockDim.x + threadIdx.x;
    int stride = gridDim.x * blockDim.x;
    for (; i < 2097152; i += stride) {
        const float* s; unsigned short* d; int j;
        if (i < 1048576)      { s = x;  d = x1;  j = i; }
        else if (i < 1835008) { s = wa; d = w1a; j = i - 1048576; }
        else                  { s = wp; d = wpb; j = i - 1835008; }
        float4 v = ((const float4*)s)[j];
        ushort4 o;
        o.x = f2bf(v.x); o.y = f2bf(v.y); o.z = f2bf(v.z); o.w = f2bf(v.w);
        ((ushort4*)d)[j] = o;
    }
}

// ---------------- GEMM: C = A[M][K] @ B[N][K]^T + bias ----------------
// 128x128 tile, BK=64, 4 waves, m97 structure + XCD-aware block swizzle.
// MODE 0: qkv epilogue -> q1 (scaled log2e) / k1 bf16 [bh][s][64],
//         vT bf16 [bh][d][2048]
// MODE 1: proj epilogue -> fp32 out [M][N]
template <int MODE>
__global__ __launch_bounds__(256, 2) void gemm_bt_kernel(
    const unsigned short* __restrict__ A,
    const unsigned short* __restrict__ Bw,
    const float* __restrict__ bias,
    unsigned short* __restrict__ q1,
    unsigned short* __restrict__ k1,
    unsigned short* __restrict__ vT,
    float* __restrict__ outp,
    int N, int K)
{
    __shared__ __align__(16) unsigned char lds[32768];
    const int t  = threadIdx.x;
    const int lane = t & 63;
    const int w  = t >> 6;
    const int wr = w >> 1, wc = w & 1;
    const int lg = lane >> 4, ll = lane & 15;

    // XCD swizzle: consecutive blocks on one XCD share an A-row panel
    const int gx = gridDim.x;
    const int flat = blockIdx.y * gx + blockIdx.x;
    const int cpx = (gx * gridDim.y) >> 3;
    const int swz = (flat & 7) * cpx + (flat >> 3);
    const int m0 = (swz / gx) * 128;
    const int n0 = (swz % gx) * 128;

    f32x4 acc[4][4] = {};

    const int srow  = t >> 3;
    const int sslot = t & 7;
    const unsigned short* Abase[4];
    const unsigned short* Bbase[4];
#pragma unroll
    for (int ci = 0; ci < 4; ++ci) {
        int r  = ci * 32 + srow;
        int cg = sslot ^ (r & 7);
        Abase[ci] = A  + (size_t)(m0 + r) * K + cg * 8;
        Bbase[ci] = Bw + (size_t)(n0 + r) * K + cg * 8;
    }

    for (int k0 = 0; k0 < K; k0 += 64) {
#pragma unroll
        for (int ci = 0; ci < 4; ++ci)
            gload_lds16(Abase[ci] + k0, lds + ci*4096 + (t>>6)*1024);
#pragma unroll
        for (int ci = 0; ci < 4; ++ci)
            gload_lds16(Bbase[ci] + k0, lds + 16384 + ci*4096 + (t>>6)*1024);
        __syncthreads();

        bf16x8 af[4][2], bfr[4][2];
#pragma unroll
        for (int mt = 0; mt < 4; ++mt)
#pragma unroll
            for (int kc = 0; kc < 2; ++kc) {
                int row = wr*64 + mt*16 + ll;
                int cg  = (4*kc + lg) ^ (row & 7);
                af[mt][kc] = *(const bf16x8*)(lds + row*128 + cg*16);
            }
#pragma unroll
        for (int nt = 0; nt < 4; ++nt)
#pragma unroll
            for (int kc = 0; kc < 2; ++kc) {
                int row = wc*64 + nt*16 + ll;
                int cg  = (4*kc + lg) ^ (row & 7);
                bfr[nt][kc] = *(const bf16x8*)(lds + 16384 + row*128 + cg*16);
            }
#pragma unroll
        for (int kc = 0; kc < 2; ++kc)
#pragma unroll
            for (int mt = 0; mt < 4; ++mt)
#pragma unroll
                for (int nt = 0; nt < 4; ++nt)
                    acc[mt][nt] = __builtin_amdgcn_mfma_f32_16x16x32_bf16(
                        af[mt][kc], bfr[nt][kc], acc[mt][nt], 0, 0, 0);
        __syncthreads();
    }

#pragma unroll
    for (int mt = 0; mt < 4; ++mt)
#pragma unroll
      for (int nt = 0; nt < 4; ++nt)
#pragma unroll
        for (int r = 0; r < 4; ++r) {
            int m = m0 + wr*64 + mt*16 + 4*lg + r;
            int n = n0 + wc*64 + nt*16 + ll;
            float v = acc[mt][nt][r] + bias[n];
            if (MODE == 0) {
                int bb = m >> 11;
                int s  = m & 2047;
                int which = n >> 10;       // 0=q 1=k 2=v
                int h  = (n >> 6) & 15;
                int d  = n & 63;
                int bh = bb * 16 + h;
                if (which == 2) {
                    vT[((size_t)bh * 64 + d) * 2048 + s] = f2bf(v);
                } else {
                    // q pre-scaled by log2(e): attn uses exp2 directly
                    float vq = (which == 0) ? v * 1.44269504f : v;
                    unsigned short* dp = (which == 0 ? q1 : k1)
                                       + ((size_t)bh * 2048 + s) * 64 + d;
                    *dp = f2bf(vq);
                }
            } else {
                outp[(size_t)m * N + n] = v;
            }
        }
}

// ---------------- flash attention v5 ----------------
// 32x32x16 MFMA, max-free softmax, denominator via ones-MFMA, hoisted
// zero-C, immediate-offset ds_reads (x2-unrolled 4-buffer rotation),
// XCD-grouped heads. grid 512 (1D), 512 thr = 8 waves, kv-split groups.
__global__ __launch_bounds__(512, 4) void attn_kernel(
    const unsigned short* __restrict__ q1,   // [bh][2048][64], pre-scaled
    const unsigned short* __restrict__ k1,   // [bh][2048][64]
    const unsigned short* __restrict__ vT,   // [bh][64][2048]
    unsigned short* __restrict__ aout)       // [b][s][h][64] bf16
{
    __shared__ __align__(16) unsigned char lds[65536];
    const int t = threadIdx.x, lane = t & 63, w = t >> 6;
    const int hi = lane >> 5, lq = lane & 31, l7 = lane & 7;
    const int gp = w >> 2, sw = w & 3;

    // block decode: all 16 q-blocks of a head on one XCD (bh%8 == XCD id)
    const int D  = blockIdx.x;
    const int bh = (D & 7) + ((D >> 7) << 3);
    const int qb = (D >> 3) & 15;
    const int q0 = qb * 128 + sw * 32;

    // Q B-frag: qf[ks][j] = Q[q0+lq][16ks + 8hi + j]
    bf16x8 qf[4];
    {
        const unsigned short* qp = q1 + ((size_t)bh*2048 + q0 + lq)*64 + hi*8;
#pragma unroll
        for (int ks = 0; ks < 4; ++ks)
            qf[ks] = *(const bf16x8*)(qp + ks*16);
    }

    f32x16 o0 = {}, o1 = {};   // PV acc: row q=(r&3)+8(r>>2)+4hi, col d=dh*32+lq
    f32x16 ld = {};            // denominator acc (ones-MFMA), same row layout
    const f32x16 fz = {};      // hoisted zero-C for QK^T chains
    bf16x8 onef;               // all-ones B-frag (bf16 1.0)
#pragma unroll
    for (int j = 0; j < 8; ++j) onef[j] = (short)0x3F80;

    // staging: 512 thr x 16B = 8KB = one tile per call.
    // K rows permuted by pi = swap(bit2,bit3) (exchange-free P->PV).
    const int sr = t >> 3, ss = t & 7;
    const int scg = ss ^ (sr & 7);
    const int psr = (sr & 51) | ((sr & 4) << 1) | ((sr & 8) >> 1);
    const unsigned short* Ksrc = k1 + ((size_t)bh*2048 + psr)*64 + scg*8;
    const unsigned short* Vsrc = vT + ((size_t)bh*64 + sr)*2048 + scg*8;
    const int sdst = w*1024;

    // per-lane fragment bases (per ks); parity/jt/dh/V become imm offsets
    unsigned char* fb0 = lds + gp*8192 + lq*128 + (((0 + hi) ^ l7) << 4);
    unsigned char* fb1 = lds + gp*8192 + lq*128 + (((2 + hi) ^ l7) << 4);
    unsigned char* fb2 = lds + gp*8192 + lq*128 + (((4 + hi) ^ l7) << 4);
    unsigned char* fb3 = lds + gp*8192 + lq*128 + (((6 + hi) ^ l7) << 4);

    // prologue: tiles 0,1 -> buffers 0,1
    gload_lds16(Ksrc,        lds + sdst);
    gload_lds16(Ksrc + 4096, lds + 8192 + sdst);
    gload_lds16(Vsrc,        lds + 32768 + sdst);
    gload_lds16(Vsrc + 64,   lds + 32768 + 8192 + sdst);
    __syncthreads();

#define ATTN_STEP(PAR)                                                        \
    {                                                                         \
        f32x16 s0, s1;                                                        \
        bf16x8 kf;                                                            \
        kf = *(const bf16x8*)(fb0 + (PAR)*16384);                             \
        s0 = __builtin_amdgcn_mfma_f32_32x32x16_bf16(kf, qf[0], fz, 0,0,0);   \
        kf = *(const bf16x8*)(fb0 + (PAR)*16384 + 4096);                      \
        s1 = __builtin_amdgcn_mfma_f32_32x32x16_bf16(kf, qf[0], fz, 0,0,0);   \
        kf = *(const bf16x8*)(fb1 + (PAR)*16384);                             \
        s0 = __builtin_amdgcn_mfma_f32_32x32x16_bf16(kf, qf[1], s0, 0,0,0);   \
        kf = *(const bf16x8*)(fb1 + (PAR)*16384 + 4096);                      \
        s1 = __builtin_amdgcn_mfma_f32_32x32x16_bf16(kf, qf[1], s1, 0,0,0);   \
        kf = *(const bf16x8*)(fb2 + (PAR)*16384);                             \
        s0 = __builtin_amdgcn_mfma_f32_32x32x16_bf16(kf, qf[2], s0, 0,0,0);   \
        kf = *(const bf16x8*)(fb2 + (PAR)*16384 + 4096);                      \
        s1 = __builtin_amdgcn_mfma_f32_32x32x16_bf16(kf, qf[2], s1, 0,0,0);   \
        kf = *(const bf16x8*)(fb3 + (PAR)*16384);                             \
        s0 = __builtin_amdgcn_mfma_f32_32x32x16_bf16(kf, qf[3], s0, 0,0,0);   \
        kf = *(const bf16x8*)(fb3 + (PAR)*16384 + 4096);                      \
        s1 = __builtin_amdgcn_mfma_f32_32x32x16_bf16(kf, qf[3], s1, 0,0,0);   \
        bf16x8 pa0, pa1, pa2, pa3;                                            \
        {                                                                     \
            union { unsigned u[4]; bf16x8 v; } a, b, c, d;                    \
            a.u[0] = cvt_pk_bf16(exp2f(s0[0]),  exp2f(s0[1]));                \
            a.u[1] = cvt_pk_bf16(exp2f(s0[2]),  exp2f(s0[3]));                \
            a.u[2] = cvt_pk_bf16(exp2f(s0[4]),  exp2f(s0[5]));                \
            a.u[3] = cvt_pk_bf16(exp2f(s0[6]),  exp2f(s0[7]));                \
            b.u[0] = cvt_pk_bf16(exp2f(s0[8]),  exp2f(s0[9]));                \
            b.u[1] = cvt_pk_bf16(exp2f(s0[10]), exp2f(s0[11]));               \
            b.u[2] = cvt_pk_bf16(exp2f(s0[12]), exp2f(s0[13]));               \
            b.u[3] = cvt_pk_bf16(exp2f(s0[14]), exp2f(s0[15]));               \
            c.u[0] = cvt_pk_bf16(exp2f(s1[0]),  exp2f(s1[1]));                \
            c.u[1] = cvt_pk_bf16(exp2f(s1[2]),  exp2f(s1[3]));                \
            c.u[2] = cvt_pk_bf16(exp2f(s1[4]),  exp2f(s1[5]));                \
            c.u[3] = cvt_pk_bf16(exp2f(s1[6]),  exp2f(s1[7]));                \
            d.u[0] = cvt_pk_bf16(exp2f(s1[8]),  exp2f(s1[9]));                \
            d.u[1] = cvt_pk_bf16(exp2f(s1[10]), exp2f(s1[11]));               \
            d.u[2] = cvt_pk_bf16(exp2f(s1[12]), exp2f(s1[13]));               \
            d.u[3] = cvt_pk_bf16(exp2f(s1[14]), exp2f(s1[15]));               \
            pa0 = a.v; pa1 = b.v; pa2 = c.v; pa3 = d.v;                       \
        }                                                                     \
        ld = __builtin_amdgcn_mfma_f32_32x32x16_bf16(pa0, onef, ld, 0,0,0);   \
        ld = __builtin_amdgcn_mfma_f32_32x32x16_bf16(pa1, onef, ld, 0,0,0);   \
        ld = __builtin_amdgcn_mfma_f32_32x32x16_bf16(pa2, onef, ld, 0,0,0);   \
        ld = __builtin_amdgcn_mfma_f32_32x32x16_bf16(pa3, onef, ld, 0,0,0);   \
        bf16x8 vf;                                                            \
        vf = *(const bf16x8*)(fb0 + (PAR)*16384 + 32768);                     \
        o0 = __builtin_amdgcn_mfma_f32_32x32x16_bf16(pa0, vf, o0, 0,0,0);     \
        vf = *(const bf16x8*)(fb0 + (PAR)*16384 + 32768 + 4096);              \
        o1 = __builtin_amdgcn_mfma_f32_32x32x16_bf16(pa0, vf, o1, 0,0,0);     \
        vf = *(const bf16x8*)(fb1 + (PAR)*16384 + 32768);                     \
        o0 = __builtin_amdgcn_mfma_f32_32x32x16_bf16(pa1, vf, o0, 0,0,0);     \
        vf = *(const bf16x8*)(fb1 + (PAR)*16384 + 32768 + 4096);              \
        o1 = __builtin_amdgcn_mfma_f32_32x32x16_bf16(pa1, vf, o1, 0,0,0);     \
        vf = *(const bf16x8*)(fb2 + (PAR)*16384 + 32768);                     \
        o0 = __builtin_amdgcn_mfma_f32_32x32x16_bf16(pa2, vf, o0, 0,0,0);     \
        vf = *(const bf16x8*)(fb2 + (PAR)*16384 + 32768 + 4096);              \
        o1 = __builtin_amdgcn_mfma_f32_32x32x16_bf16(pa2, vf, o1, 0,0,0);     \
        vf = *(const bf16x8*)(fb3 + (PAR)*16384 + 32768);                     \
        o0 = __builtin_amdgcn_mfma_f32_32x32x16_bf16(pa3, vf, o0, 0,0,0);     \
        vf = *(const bf16x8*)(fb3 + (PAR)*16384 + 32768 + 4096);              \
        o1 = __builtin_amdgcn_mfma_f32_32x32x16_bf16(pa3, vf, o1, 0,0,0);     \
    }

    for (int sp = 0; sp < 8; ++sp) {
        // half A: s=2sp, par=0; stage tiles 4sp+2,4sp+3 -> buffers 2,3
        {
            const size_t T = 4*(size_t)sp + 2;
            gload_lds16(Ksrc + T*4096,        lds + 16384 + sdst);
            gload_lds16(Ksrc + T*4096 + 4096, lds + 24576 + sdst);
            gload_lds16(Vsrc + T*64,          lds + 32768 + 16384 + sdst);
            gload_lds16(Vsrc + T*64 + 64,     lds + 32768 + 24576 + sdst);
            ATTN_STEP(0)
            __syncthreads();
        }
        // half B: s=2sp+1, par=1; stage tiles 4sp+4,4sp+5 -> buffers 0,1
        {
            if (sp < 7) {
                const size_t T = 4*(size_t)sp + 4;
                gload_lds16(Ksrc + T*4096,        lds + sdst);
                gload_lds16(Ksrc + T*4096 + 4096, lds + 8192 + sdst);
                gload_lds16(Vsrc + T*64,          lds + 32768 + sdst);
                gload_lds16(Vsrc + T*64 + 64,     lds + 32768 + 8192 + sdst);
            }
            ATTN_STEP(1)
            __syncthreads();
        }
    }
#undef ATTN_STEP

    // ---- combine kv-split partials (pure add: max-free softmax) ----
    float* mb = (float*)lds;
    if (gp == 1) {
        float* p = mb + ((sw << 6) + lane) * 48;
#pragma unroll
        for (int c = 0; c < 4; ++c) {
            f32x4 v = { o0[4*c], o0[4*c+1], o0[4*c+2], o0[4*c+3] };
            *(f32x4*)(p + 4*c) = v;
        }
#pragma unroll
        for (int c = 0; c < 4; ++c) {
            f32x4 v = { o1[4*c], o1[4*c+1], o1[4*c+2], o1[4*c+3] };
            *(f32x4*)(p + 16 + 4*c) = v;
        }
#pragma unroll
        for (int c = 0; c < 4; ++c) {
            f32x4 v = { ld[4*c], ld[4*c+1], ld[4*c+2], ld[4*c+3] };
            *(f32x4*)(p + 32 + 4*c) = v;
        }
    }
    __syncthreads();
    if (gp == 0) {
        const float* p = mb + ((sw << 6) + lane) * 48;
#pragma unroll
        for (int c = 0; c < 4; ++c) {
            f32x4 v = *(const f32x4*)(p + 4*c);
            o0[4*c] += v[0]; o0[4*c+1] += v[1]; o0[4*c+2] += v[2]; o0[4*c+3] += v[3];
        }
#pragma unroll
        for (int c = 0; c < 4; ++c) {
            f32x4 v = *(const f32x4*)(p + 16 + 4*c);
            o1[4*c] += v[0]; o1[4*c+1] += v[1]; o1[4*c+2] += v[2]; o1[4*c+3] += v[3];
        }
#pragma unroll
        for (int c = 0; c < 4; ++c) {
            f32x4 v = *(const f32x4*)(p + 32 + 4*c);
            ld[4*c] += v[0]; ld[4*c+1] += v[1]; ld[4*c+2] += v[2]; ld[4*c+3] += v[3];
        }

        const int bb = bh >> 4, h = bh & 15;
#pragma unroll
        for (int r = 0; r < 16; ++r) {
            int qrow = (r & 3) + 8*(r >> 2) + 4*hi;
            float linv = 1.0f / ld[r];
            size_t srow = q0 + qrow;
            aout[((size_t)(bb*2048 + srow)*16 + h)*64 + lq]      = f2bf(o0[r] * linv);
            aout[((size_t)(bb*2048 + srow)*16 + h)*64 + 32 + lq] = f2bf(o1[r] * linv);
        }
    }
}

// ---------------- launch ----------------
extern "C" void kernel_launch(void* const* d_in, const int* in_sizes, int n_in,
                              void* d_out, int out_size, void* d_ws, size_t ws_size,
                              hipStream_t stream) {
    const float* x      = (const float*)d_in[0];
    const float* w_attn = (const float*)d_in[1];
    const float* b_attn = (const float*)d_in[2];
    const float* w_proj = (const float*)d_in[3];
    const float* b_proj = (const float*)d_in[4];
    float* out = (float*)d_out;

    // ws (MB): x1 0..8, w1a 8..14, wpb 14..16, q1 16..24, k1 24..32,
    // vT 32..40, ab 40..48
    unsigned char* ws = (unsigned char*)d_ws;
    unsigned short* x1  = (unsigned short*)(ws);
    unsigned short* w1a = (unsigned short*)(ws + (size_t)8*1024*1024);
    unsigned short* wpb = (unsigned short*)(ws + (size_t)14*1024*1024);
    unsigned short* q1  = (unsigned short*)(ws + (size_t)16*1024*1024);
    unsigned short* k1  = (unsigned short*)(ws + (size_t)24*1024*1024);
    unsigned short* vT  = (unsigned short*)(ws + (size_t)32*1024*1024);
    unsigned short* ab  = (unsigned short*)(ws + (size_t)40*1024*1024);

    conv_all_kernel<<<2048, 256, 0, stream>>>(x, w_attn, w_proj, x1, w1a, wpb);

    gemm_bt_kernel<0><<<dim3(24, 32), 256, 0, stream>>>(
        x1, w1a, b_attn, q1, k1, vT, nullptr, 3072, 1024);

    attn_kernel<<<512, 512, 0, stream>>>(q1, k1, vT, ab);

    gemm_bt_kernel<1><<<dim3(8, 32), 256, 0, stream>>>(
        ab, wpb, b_proj, nullptr, nullptr, nullptr, out, 1024, 1024);
}

// Round 6
// 119.687 us; speedup vs baseline: 1.9156x; 1.0465x over previous
//
#include <hip/hip_runtime.h>
#include <hip/hip_bf16.h>
#include <stdint.h>
#include <math.h>

// x[2,2048,1024], w_attn[3072,1024], b_attn[3072], w_proj[1024,1024],
// b_proj[1024] -> out fp32 [2,2048,1024]. H=16, hd=64, NO scale, NO mask.

typedef __attribute__((ext_vector_type(2))) float f32x2;
typedef __attribute__((ext_vector_type(4))) float f32x4;
typedef __attribute__((ext_vector_type(16))) float f32x16;
typedef __attribute__((ext_vector_type(8))) short bf16x8;

static __device__ __forceinline__ unsigned short f2bf(float f) {
    unsigned u = __float_as_uint(f);
    u += 0x7FFFu + ((u >> 16) & 1u);          // RNE
    return (unsigned short)(u >> 16);
}
static __device__ __forceinline__ unsigned cvt_pk_bf16(float a, float b) {
    unsigned r;   // r = {lo16: bf16(a), hi16: bf16(b)}
    asm("v_cvt_pk_bf16_f32 %0, %1, %2" : "=v"(r) : "v"(a), "v"(b));
    return r;
}

typedef const __attribute__((address_space(1))) unsigned int* gas_ptr;
typedef __attribute__((address_space(3))) unsigned int* las_ptr;
static __device__ __forceinline__ void gload_lds16(const void* g, void* l) {
    __builtin_amdgcn_global_load_lds((gas_ptr)g, (las_ptr)l, 16, 0, 0);
}

// ---------------- fused fp32 -> bf16 convert (x, w_attn, w_proj) ----------------
__global__ void conv_all_kernel(const float* __restrict__ x,
                                const float* __restrict__ wa,
                                const float* __restrict__ wp,
                                unsigned short* __restrict__ x1,
                                unsigned short* __restrict__ w1a,
                                unsigned short* __restrict__ wpb) {
    int i = blockIdx.x * blockDim.x + threadIdx.x;
    int stride = gridDim.x * blockDim.x;
    for (; i < 2097152; i += stride) {
        const float* s; unsigned short* d; int j;
        if (i < 1048576)      { s = x;  d = x1;  j = i; }
        else if (i < 1835008) { s = wa; d = w1a; j = i - 1048576; }
        else                  { s = wp; d = wpb; j = i - 1835008; }
        float4 v = ((const float4*)s)[j];
        ushort4 o;
        o.x = f2bf(v.x); o.y = f2bf(v.y); o.z = f2bf(v.z); o.w = f2bf(v.w);
        ((ushort4*)d)[j] = o;
    }
}

// ---------------- GEMM: C = A[M][K] @ B[N][K]^T + bias ----------------
// 128x128 tile, BK=64, 4 waves, m97 structure + XCD-aware block swizzle.
// MODE 0: qkv epilogue -> q1 (scaled log2e) / k1 bf16 [bh][s][64],
//         vT bf16 [bh][d][2048]
// MODE 1: proj epilogue -> fp32 out [M][N]
template <int MODE>
__global__ __launch_bounds__(256, 2) void gemm_bt_kernel(
    const unsigned short* __restrict__ A,
    const unsigned short* __restrict__ Bw,
    const float* __restrict__ bias,
    unsigned short* __restrict__ q1,
    unsigned short* __restrict__ k1,
    unsigned short* __restrict__ vT,
    float* __restrict__ outp,
    int N, int K)
{
    __shared__ __align__(16) unsigned char lds[32768];
    const int t  = threadIdx.x;
    const int lane = t & 63;
    const int w  = t >> 6;
    const int wr = w >> 1, wc = w & 1;
    const int lg = lane >> 4, ll = lane & 15;

    // XCD swizzle: consecutive blocks on one XCD share an A-row panel
    const int gx = gridDim.x;
    const int flat = blockIdx.y * gx + blockIdx.x;
    const int cpx = (gx * gridDim.y) >> 3;
    const int swz = (flat & 7) * cpx + (flat >> 3);
    const int m0 = (swz / gx) * 128;
    const int n0 = (swz % gx) * 128;

    f32x4 acc[4][4] = {};

    const int srow  = t >> 3;
    const int sslot = t & 7;
    const unsigned short* Abase[4];
    const unsigned short* Bbase[4];
#pragma unroll
    for (int ci = 0; ci < 4; ++ci) {
        int r  = ci * 32 + srow;
        int cg = sslot ^ (r & 7);
        Abase[ci] = A  + (size_t)(m0 + r) * K + cg * 8;
        Bbase[ci] = Bw + (size_t)(n0 + r) * K + cg * 8;
    }

    for (int k0 = 0; k0 < K; k0 += 64) {
#pragma unroll
        for (int ci = 0; ci < 4; ++ci)
            gload_lds16(Abase[ci] + k0, lds + ci*4096 + (t>>6)*1024);
#pragma unroll
        for (int ci = 0; ci < 4; ++ci)
            gload_lds16(Bbase[ci] + k0, lds + 16384 + ci*4096 + (t>>6)*1024);
        __syncthreads();

        bf16x8 af[4][2], bfr[4][2];
#pragma unroll
        for (int mt = 0; mt < 4; ++mt)
#pragma unroll
            for (int kc = 0; kc < 2; ++kc) {
                int row = wr*64 + mt*16 + ll;
                int cg  = (4*kc + lg) ^ (row & 7);
                af[mt][kc] = *(const bf16x8*)(lds + row*128 + cg*16);
            }
#pragma unroll
        for (int nt = 0; nt < 4; ++nt)
#pragma unroll
            for (int kc = 0; kc < 2; ++kc) {
                int row = wc*64 + nt*16 + ll;
                int cg  = (4*kc + lg) ^ (row & 7);
                bfr[nt][kc] = *(const bf16x8*)(lds + 16384 + row*128 + cg*16);
            }
#pragma unroll
        for (int kc = 0; kc < 2; ++kc)
#pragma unroll
            for (int mt = 0; mt < 4; ++mt)
#pragma unroll
                for (int nt = 0; nt < 4; ++nt)
                    acc[mt][nt] = __builtin_amdgcn_mfma_f32_16x16x32_bf16(
                        af[mt][kc], bfr[nt][kc], acc[mt][nt], 0, 0, 0);
        __syncthreads();
    }

#pragma unroll
    for (int mt = 0; mt < 4; ++mt)
#pragma unroll
      for (int nt = 0; nt < 4; ++nt)
#pragma unroll
        for (int r = 0; r < 4; ++r) {
            int m = m0 + wr*64 + mt*16 + 4*lg + r;
            int n = n0 + wc*64 + nt*16 + ll;
            float v = acc[mt][nt][r] + bias[n];
            if (MODE == 0) {
                int bb = m >> 11;
                int s  = m & 2047;
                int which = n >> 10;       // 0=q 1=k 2=v
                int h  = (n >> 6) & 15;
                int d  = n & 63;
                int bh = bb * 16 + h;
                if (which == 2) {
                    vT[((size_t)bh * 64 + d) * 2048 + s] = f2bf(v);
                } else {
                    // q pre-scaled by log2(e): attn uses exp2 directly
                    float vq = (which == 0) ? v * 1.44269504f : v;
                    unsigned short* dp = (which == 0 ? q1 : k1)
                                       + ((size_t)bh * 2048 + s) * 64 + d;
                    *dp = f2bf(vq);
                }
            } else {
                outp[(size_t)m * N + n] = v;
            }
        }
}

// ---------------- flash attention v6 ----------------
// 32x32x16 MFMA, max-free softmax (raw-exp2 f32x2 denominator, deferred
// half-merge), hoisted zero-C, immediate-offset ds_reads, setprio around
// MFMA clusters, XCD-grouped heads, kv-split groups.
__global__ __launch_bounds__(512, 4) void attn_kernel(
    const unsigned short* __restrict__ q1,   // [bh][2048][64], pre-scaled
    const unsigned short* __restrict__ k1,   // [bh][2048][64]
    const unsigned short* __restrict__ vT,   // [bh][64][2048]
    unsigned short* __restrict__ aout)       // [b][s][h][64] bf16
{
    __shared__ __align__(16) unsigned char lds[65536];
    const int t = threadIdx.x, lane = t & 63, w = t >> 6;
    const int hi = lane >> 5, lq = lane & 31, l7 = lane & 7;
    const int gp = w >> 2, sw = w & 3;

    // block decode: all 16 q-blocks of a head on one XCD (bh%8 == XCD id)
    const int D  = blockIdx.x;
    const int bh = (D & 7) + ((D >> 7) << 3);
    const int qb = (D >> 3) & 15;
    const int q0 = qb * 128 + sw * 32;

    // Q B-frag: qf[ks][j] = Q[q0+lq][16ks + 8hi + j]
    bf16x8 qf[4];
    {
        const unsigned short* qp = q1 + ((size_t)bh*2048 + q0 + lq)*64 + hi*8;
#pragma unroll
        for (int ks = 0; ks < 4; ++ks)
            qf[ks] = *(const bf16x8*)(qp + ks*16);
    }

    f32x16 o0 = {}, o1 = {};   // PV acc: row q=(r&3)+8(r>>2)+4hi, col d=dh*32+lq
    f32x2 lr2 = {0.f, 0.f};    // raw-exp2 denominator partial (per lane)
    const f32x16 fz = {};      // hoisted zero-C for QK^T chains

    // staging: 512 thr x 16B = 8KB = one tile per call.
    // K rows permuted by pi = swap(bit2,bit3) (exchange-free P->PV).
    const int sr = t >> 3, ss = t & 7;
    const int scg = ss ^ (sr & 7);
    const int psr = (sr & 51) | ((sr & 4) << 1) | ((sr & 8) >> 1);
    const unsigned short* Ksrc = k1 + ((size_t)bh*2048 + psr)*64 + scg*8;
    const unsigned short* Vsrc = vT + ((size_t)bh*64 + sr)*2048 + scg*8;
    const int sdst = w*1024;

    // per-lane fragment bases (per ks); parity/jt/dh/V become imm offsets
    unsigned char* fb0 = lds + gp*8192 + lq*128 + (((0 + hi) ^ l7) << 4);
    unsigned char* fb1 = lds + gp*8192 + lq*128 + (((2 + hi) ^ l7) << 4);
    unsigned char* fb2 = lds + gp*8192 + lq*128 + (((4 + hi) ^ l7) << 4);
    unsigned char* fb3 = lds + gp*8192 + lq*128 + (((6 + hi) ^ l7) << 4);

    // prologue: tiles 0,1 -> buffers 0,1
    gload_lds16(Ksrc,        lds + sdst);
    gload_lds16(Ksrc + 4096, lds + 8192 + sdst);
    gload_lds16(Vsrc,        lds + 32768 + sdst);
    gload_lds16(Vsrc + 64,   lds + 32768 + 8192 + sdst);
    __syncthreads();

#define SOFT_PACK(SV, PA, PB)                                                 \
    {                                                                         \
        float e0 =exp2f(SV[0]),  e1 =exp2f(SV[1]),  e2 =exp2f(SV[2]);         \
        float e3 =exp2f(SV[3]),  e4 =exp2f(SV[4]),  e5 =exp2f(SV[5]);         \
        float e6 =exp2f(SV[6]),  e7 =exp2f(SV[7]),  e8 =exp2f(SV[8]);         \
        float e9 =exp2f(SV[9]),  e10=exp2f(SV[10]), e11=exp2f(SV[11]);        \
        float e12=exp2f(SV[12]), e13=exp2f(SV[13]), e14=exp2f(SV[14]);        \
        float e15=exp2f(SV[15]);                                              \
        union { unsigned u[4]; bf16x8 v; } A_, B_;                            \
        A_.u[0]=cvt_pk_bf16(e0,e1);   A_.u[1]=cvt_pk_bf16(e2,e3);             \
        A_.u[2]=cvt_pk_bf16(e4,e5);   A_.u[3]=cvt_pk_bf16(e6,e7);             \
        B_.u[0]=cvt_pk_bf16(e8,e9);   B_.u[1]=cvt_pk_bf16(e10,e11);           \
        B_.u[2]=cvt_pk_bf16(e12,e13); B_.u[3]=cvt_pk_bf16(e14,e15);           \
        PA = A_.v; PB = B_.v;                                                 \
        f32x2 p0 = {e0,e1};   p0 += (f32x2){e2,e3};                           \
        p0 += (f32x2){e4,e5};   p0 += (f32x2){e6,e7};                         \
        p0 += (f32x2){e8,e9};   p0 += (f32x2){e10,e11};                       \
        p0 += (f32x2){e12,e13}; p0 += (f32x2){e14,e15};                       \
        lr2 += p0;                                                            \
    }

#define ATTN_STEP(PAR)                                                        \
    {                                                                         \
        f32x16 s0, s1;                                                        \
        bf16x8 kf;                                                            \
        __builtin_amdgcn_s_setprio(1);                                        \
        kf = *(const bf16x8*)(fb0 + (PAR)*16384);                             \
        s0 = __builtin_amdgcn_mfma_f32_32x32x16_bf16(kf, qf[0], fz, 0,0,0);   \
        kf = *(const bf16x8*)(fb0 + (PAR)*16384 + 4096);                      \
        s1 = __builtin_amdgcn_mfma_f32_32x32x16_bf16(kf, qf[0], fz, 0,0,0);   \
        kf = *(const bf16x8*)(fb1 + (PAR)*16384);                             \
        s0 = __builtin_amdgcn_mfma_f32_32x32x16_bf16(kf, qf[1], s0, 0,0,0);   \
        kf = *(const bf16x8*)(fb1 + (PAR)*16384 + 4096);                      \
        s1 = __builtin_amdgcn_mfma_f32_32x32x16_bf16(kf, qf[1], s1, 0,0,0);   \
        kf = *(const bf16x8*)(fb2 + (PAR)*16384);                             \
        s0 = __builtin_amdgcn_mfma_f32_32x32x16_bf16(kf, qf[2], s0, 0,0,0);   \
        kf = *(const bf16x8*)(fb2 + (PAR)*16384 + 4096);                      \
        s1 = __builtin_amdgcn_mfma_f32_32x32x16_bf16(kf, qf[2], s1, 0,0,0);   \
        kf = *(const bf16x8*)(fb3 + (PAR)*16384);                             \
        s0 = __builtin_amdgcn_mfma_f32_32x32x16_bf16(kf, qf[3], s0, 0,0,0);   \
        kf = *(const bf16x8*)(fb3 + (PAR)*16384 + 4096);                      \
        s1 = __builtin_amdgcn_mfma_f32_32x32x16_bf16(kf, qf[3], s1, 0,0,0);   \
        __builtin_amdgcn_s_setprio(0);                                        \
        bf16x8 pa0, pa1, pa2, pa3;                                            \
        SOFT_PACK(s0, pa0, pa1)                                               \
        SOFT_PACK(s1, pa2, pa3)                                               \
        bf16x8 vf;                                                            \
        __builtin_amdgcn_s_setprio(1);                                        \
        vf = *(const bf16x8*)(fb0 + (PAR)*16384 + 32768);                     \
        o0 = __builtin_amdgcn_mfma_f32_32x32x16_bf16(pa0, vf, o0, 0,0,0);     \
        vf = *(const bf16x8*)(fb0 + (PAR)*16384 + 32768 + 4096);              \
        o1 = __builtin_amdgcn_mfma_f32_32x32x16_bf16(pa0, vf, o1, 0,0,0);     \
        vf = *(const bf16x8*)(fb1 + (PAR)*16384 + 32768);                     \
        o0 = __builtin_amdgcn_mfma_f32_32x32x16_bf16(pa1, vf, o0, 0,0,0);     \
        vf = *(const bf16x8*)(fb1 + (PAR)*16384 + 32768 + 4096);              \
        o1 = __builtin_amdgcn_mfma_f32_32x32x16_bf16(pa1, vf, o1, 0,0,0);     \
        vf = *(const bf16x8*)(fb2 + (PAR)*16384 + 32768);                     \
        o0 = __builtin_amdgcn_mfma_f32_32x32x16_bf16(pa2, vf, o0, 0,0,0);     \
        vf = *(const bf16x8*)(fb2 + (PAR)*16384 + 32768 + 4096);              \
        o1 = __builtin_amdgcn_mfma_f32_32x32x16_bf16(pa2, vf, o1, 0,0,0);     \
        vf = *(const bf16x8*)(fb3 + (PAR)*16384 + 32768);                     \
        o0 = __builtin_amdgcn_mfma_f32_32x32x16_bf16(pa3, vf, o0, 0,0,0);     \
        vf = *(const bf16x8*)(fb3 + (PAR)*16384 + 32768 + 4096);              \
        o1 = __builtin_amdgcn_mfma_f32_32x32x16_bf16(pa3, vf, o1, 0,0,0);     \
        __builtin_amdgcn_s_setprio(0);                                        \
    }

    for (int sp = 0; sp < 8; ++sp) {
        // half A: s=2sp, par=0; stage tiles 4sp+2,4sp+3 -> buffers 2,3
        {
            const size_t T = 4*(size_t)sp + 2;
            gload_lds16(Ksrc + T*4096,        lds + 16384 + sdst);
            gload_lds16(Ksrc + T*4096 + 4096, lds + 24576 + sdst);
            gload_lds16(Vsrc + T*64,          lds + 32768 + 16384 + sdst);
            gload_lds16(Vsrc + T*64 + 64,     lds + 32768 + 24576 + sdst);
            ATTN_STEP(0)
            __syncthreads();
        }
        // half B: s=2sp+1, par=1; stage tiles 4sp+4,4sp+5 -> buffers 0,1
        {
            if (sp < 7) {
                const size_t T = 4*(size_t)sp + 4;
                gload_lds16(Ksrc + T*4096,        lds + sdst);
                gload_lds16(Ksrc + T*4096 + 4096, lds + 8192 + sdst);
                gload_lds16(Vsrc + T*64,          lds + 32768 + sdst);
                gload_lds16(Vsrc + T*64 + 64,     lds + 32768 + 8192 + sdst);
            }
            ATTN_STEP(1)
            __syncthreads();
        }
    }
#undef ATTN_STEP
#undef SOFT_PACK

    // denominator: merge pair lanes + the two kv halves (linear sum)
    float lrow = lr2[0] + lr2[1];
    lrow += __shfl_xor(lrow, 32);

    // ---- combine kv-split partials (pure add: max-free softmax) ----
    float* mb = (float*)lds;
    const int slot = (sw << 6) + lane;
    if (gp == 1) {
        float* p = mb + slot * 32;
#pragma unroll
        for (int c = 0; c < 4; ++c) {
            f32x4 v = { o0[4*c], o0[4*c+1], o0[4*c+2], o0[4*c+3] };
            *(f32x4*)(p + 4*c) = v;
        }
#pragma unroll
        for (int c = 0; c < 4; ++c) {
            f32x4 v = { o1[4*c], o1[4*c+1], o1[4*c+2], o1[4*c+3] };
            *(f32x4*)(p + 16 + 4*c) = v;
        }
        mb[8192 + slot] = lrow;
    }
    __syncthreads();
    if (gp == 0) {
        const float* p = mb + slot * 32;
#pragma unroll
        for (int c = 0; c < 4; ++c) {
            f32x4 v = *(const f32x4*)(p + 4*c);
            o0[4*c] += v[0]; o0[4*c+1] += v[1]; o0[4*c+2] += v[2]; o0[4*c+3] += v[3];
        }
#pragma unroll
        for (int c = 0; c < 4; ++c) {
            f32x4 v = *(const f32x4*)(p + 16 + 4*c);
            o1[4*c] += v[0]; o1[4*c+1] += v[1]; o1[4*c+2] += v[2]; o1[4*c+3] += v[3];
        }
        lrow += mb[8192 + slot];

        const int bb = bh >> 4, h = bh & 15;
#pragma unroll
        for (int r = 0; r < 16; ++r) {
            int qrow = (r & 3) + 8*(r >> 2) + 4*hi;
            float linv = 1.0f / __shfl(lrow, qrow);
            size_t srow = q0 + qrow;
            aout[((size_t)(bb*2048 + srow)*16 + h)*64 + lq]      = f2bf(o0[r] * linv);
            aout[((size_t)(bb*2048 + srow)*16 + h)*64 + 32 + lq] = f2bf(o1[r] * linv);
        }
    }
}

// ---------------- launch ----------------
extern "C" void kernel_launch(void* const* d_in, const int* in_sizes, int n_in,
                              void* d_out, int out_size, void* d_ws, size_t ws_size,
                              hipStream_t stream) {
    const float* x      = (const float*)d_in[0];
    const float* w_attn = (const float*)d_in[1];
    const float* b_attn = (const float*)d_in[2];
    const float* w_proj = (const float*)d_in[3];
    const float* b_proj = (const float*)d_in[4];
    float* out = (float*)d_out;

    // ws (MB): x1 0..8, w1a 8..14, wpb 14..16, q1 16..24, k1 24..32,
    // vT 32..40, ab 40..48
    unsigned char* ws = (unsigned char*)d_ws;
    unsigned short* x1  = (unsigned short*)(ws);
    unsigned short* w1a = (unsigned short*)(ws + (size_t)8*1024*1024);
    unsigned short* wpb = (unsigned short*)(ws + (size_t)14*1024*1024);
    unsigned short* q1  = (unsigned short*)(ws + (size_t)16*1024*1024);
    unsigned short* k1  = (unsigned short*)(ws + (size_t)24*1024*1024);
    unsigned short* vT  = (unsigned short*)(ws + (size_t)32*1024*1024);
    unsigned short* ab  = (unsigned short*)(ws + (size_t)40*1024*1024);

    conv_all_kernel<<<2048, 256, 0, stream>>>(x, w_attn, w_proj, x1, w1a, wpb);

    gemm_bt_kernel<0><<<dim3(24, 32), 256, 0, stream>>>(
        x1, w1a, b_attn, q1, k1, vT, nullptr, 3072, 1024);

    attn_kernel<<<512, 512, 0, stream>>>(q1, k1, vT, ab);

    gemm_bt_kernel<1><<<dim3(8, 32), 256, 0, stream>>>(
        ab, wpb, b_proj, nullptr, nullptr, nullptr, out, 1024, 1024);
}